// Round 9
// baseline (846.290 us; speedup 1.0000x reference)
//
#include <hip/hip_runtime.h>
#include <hip/hip_bf16.h>

typedef __hip_bfloat16 bf16;
typedef __bf16 bf16x8 __attribute__((ext_vector_type(8)));
typedef float f32x4 __attribute__((ext_vector_type(4)));

// B=8, C=256, H=W=64, nh=4, HD=64, coarse tokens N=1024 (32x32), kf=256, fine tokens 1024.
// fp32 in/out (auto-detected). Top-k-critical paths (down-conv, attention QK^T) use bf16x2
// split-precision MFMA (error ~2^-17, fp32-class => tie-safe); PV + post-topk GEMMs plain bf16 MFMA.

// ---------------- workspace layout (float offsets) ----------------
#define OFF_XDHWC    0L
#define OFF_QH       2097152L     // 5 planes (ushort units vs this base):
                                  //   QH +0, QL +2097152, KH +4194304, KL +6291456, VT +8388608
#define OFF_T1       0L           // overlay on trunk
#define OFF_OUTC     8388608L
#define OFF_COARSE   10485760L    // XHL (packed hi|lo x) first, then PSCW, then coarse NCHW -> y
#define OFF_XHL      10485760L    // 8,388,608 uint (hi|lo packed bf16 of x, NCHW)
#define OFF_PSCW     10485760L    // 2M floats: per-(bh,rt,wave) colsum partials (XHL dead by then)
#define OFF_SCORE    19398656L
#define OFF_TOPK     19431424L
#define OFF_DOWNW    19439616L    // WH bf16 [co][k] (1M ushort); WL at +524288 floats
#define OFF_DOWNWL   19963904L
#define OFF_UPW4     20488192L    // bf16 (ushort) [cls][co][k]
#define OFF_WQKVC    21536768L
#define OFF_BQKVC    21549056L
#define OFF_WQKVF    21549248L
#define OFF_BQKVF    21561536L
#define OFF_PWW      21561728L    // bf16 (ushort) [co][ci]
#define OFF_DWW      21627264L
#define OFF_BN1S     21629568L
#define OFF_BN1T     21629824L
#define OFF_BN2S     21630080L
#define OFF_BN2T     21630336L
#define OFF_DOWNB    21630592L
#define OFF_UPB      21630848L
#define OFF_FLAG     21631104L    // 1 int: 1 = bf16 world, 0 = fp32 world (default via memset)
#define WS_FLOATS    21631360L

__device__ __forceinline__ float relu6(float v) { return v < 0.f ? 0.f : (v > 6.f ? 6.f : v); }

__device__ __forceinline__ float ldin(const void* p, long i, int flag) {
    return flag ? __bfloat162float(((const bf16*)p)[i]) : ((const float*)p)[i];
}

// fp32 -> bf16 bits, round-to-nearest-even
__device__ __forceinline__ unsigned short f2bf(float f) {
    unsigned int b = __float_as_uint(f);
    b += 0x7FFFu + ((b >> 16) & 1u);
    return (unsigned short)(b >> 16);
}

// ---------------- dtype detector ----------------
__global__ __launch_bounds__(256) void detect_kernel(const void* __restrict__ x, int* __restrict__ flag) {
    __shared__ int cnt[256];
    int tid = threadIdx.x;
    int c = 0;
    for (int i = tid; i < 4096; i += 256) {
        long idx = (long)i * 2047;
        float v = __bfloat162float(((const bf16*)x)[idx]);
        float a = fabsf(v);
        if (isfinite(v) && a > 1e-8f && a < 100.f) c++;
    }
    cnt[tid] = c; __syncthreads();
    for (int s = 128; s > 0; s >>= 1) { if (tid < s) cnt[tid] += cnt[tid + s]; __syncthreads(); }
    if (tid == 0 && cnt[0] >= 3686) *flag = 1;
}

// ---------------- prep kernels (dual-dtype) ----------------
// split to packed hi|lo uint (x): low16 = bf16(v), high16 = bf16(v - hi)
__global__ __launch_bounds__(256) void split_pack_kernel(const void* __restrict__ in, unsigned int* __restrict__ out,
                                                         int n, const int* __restrict__ flagp) {
    int flag = *flagp;
    int i = blockIdx.x * 256 + threadIdx.x;
    if (i < n) {
        float v = ldin(in, i, flag);
        unsigned short h = f2bf(v);
        float fh = __uint_as_float(((unsigned int)h) << 16);
        unsigned short l = f2bf(v - fh);
        out[i] = (unsigned int)h | ((unsigned int)l << 16);
    }
}

// split to separate hi/lo planes (down_w, layout [co][k] is identity with input flat layout)
__global__ __launch_bounds__(256) void split_kernel(const void* __restrict__ in,
                                                    unsigned short* __restrict__ hi, unsigned short* __restrict__ lo,
                                                    int n, const int* __restrict__ flagp) {
    int flag = *flagp;
    int i = blockIdx.x * 256 + threadIdx.x;
    if (i < n) {
        float v = ldin(in, i, flag);
        unsigned short h = f2bf(v);
        float fh = __uint_as_float(((unsigned int)h) << 16);
        hi[i] = h;
        lo[i] = f2bf(v - fh);
    }
}

// up_w [ci,co,4,4] -> W4 bf16 [cls][co][ci*4+j]
__global__ __launch_bounds__(256) void prep_up_kernel(const void* __restrict__ w, unsigned short* __restrict__ W4,
                                                      const int* __restrict__ flagp) {
    int flag = *flagp;
    int idx = blockIdx.x * 256 + threadIdx.x;
    int cls = idx >> 18; int rem = idx & 262143;
    int co = rem >> 10; int q = rem & 1023;
    int ci = q >> 2; int j = q & 3;
    int pa = cls >> 1, pb = cls & 1;
    int jy = j >> 1, jx = j & 1;
    int ky = (pa == 0) ? (jy ? 3 : 1) : (jy ? 0 : 2);
    int kx = (pb == 0) ? (jx ? 3 : 1) : (jx ? 0 : 2);
    W4[idx] = f2bf(ldin(w, (((long)ci * 256 + co) * 4 + ky) * 4 + kx, flag));
}

// fused small-tensor prep: tqkv_c, tqkv_f, dw_w, biases, bn1/bn2, pw_w (replaces 10 launches)
__global__ __launch_bounds__(256) void prep_misc_kernel(
    const void* __restrict__ down_b, const void* __restrict__ up_b,
    const void* __restrict__ bqkv_c, const void* __restrict__ bqkv_f,
    const void* __restrict__ dw_w, const void* __restrict__ wqkv_c,
    const void* __restrict__ wqkv_f, const void* __restrict__ pw_w,
    const void* __restrict__ bn1_g, const void* __restrict__ bn1_b,
    const void* __restrict__ bn1_m, const void* __restrict__ bn1_v,
    const void* __restrict__ bn2_g, const void* __restrict__ bn2_b,
    const void* __restrict__ bn2_m, const void* __restrict__ bn2_v,
    float* __restrict__ ws, const int* __restrict__ flagp)
{
    int flag = *flagp;
    int bid = blockIdx.x, tid = threadIdx.x;
    if (bid < 48) {                        // wqkv_c transpose -> [j][d]
        int idx = bid * 256 + tid;
        int j = idx >> 6, d = idx & 63;
        ws[OFF_WQKVC + idx] = ldin(wqkv_c, d * 192 + j, flag);
    } else if (bid < 96) {                 // wqkv_f transpose
        int idx = (bid - 48) * 256 + tid;
        int j = idx >> 6, d = idx & 63;
        ws[OFF_WQKVF + idx] = ldin(wqkv_f, d * 192 + j, flag);
    } else if (bid < 105) {                // dw_w cvt (2304)
        int i = (bid - 96) * 256 + tid;
        if (i < 2304) ws[OFF_DWW + i] = ldin(dw_w, i, flag);
    } else if (bid == 105) {
        ws[OFF_DOWNB + tid] = ldin(down_b, tid, flag);
    } else if (bid == 106) {
        ws[OFF_UPB + tid] = ldin(up_b, tid, flag);
    } else if (bid == 107) {
        if (tid < 192) ws[OFF_BQKVC + tid] = ldin(bqkv_c, tid, flag);
    } else if (bid == 108) {
        if (tid < 192) ws[OFF_BQKVF + tid] = ldin(bqkv_f, tid, flag);
    } else if (bid == 109) {               // bn1 prep
        float gv = ldin(bn1_g, tid, flag), bv = ldin(bn1_b, tid, flag);
        float mv = ldin(bn1_m, tid, flag), vv = ldin(bn1_v, tid, flag);
        float inv = gv / sqrtf(vv + 1e-5f);
        ws[OFF_BN1S + tid] = inv; ws[OFF_BN1T + tid] = bv - mv * inv;
    } else if (bid == 110) {               // bn2 prep
        float gv = ldin(bn2_g, tid, flag), bv = ldin(bn2_b, tid, flag);
        float mv = ldin(bn2_m, tid, flag), vv = ldin(bn2_v, tid, flag);
        float inv = gv / sqrtf(vv + 1e-5f);
        ws[OFF_BN2S + tid] = inv; ws[OFF_BN2T + tid] = bv - mv * inv;
    } else {                               // pw_w -> bf16 (65536), blocks 111..366
        int i = (bid - 111) * 256 + tid;
        ((unsigned short*)(ws + OFF_PWW))[i] = f2bf(ldin(pw_w, i, flag));
    }
}

// ---------------- bf16x2 split-precision MFMA down-conv (top-k-safe) ----------------
// R1-exact structure (best measured: 122.9us): 64x64 tile, BK=32, grid 4x128.
// C[m,n] = conv; m=(b,oy,ox) M=8192, n=co N=256, k=(ci,ky,kx) K=4096.
// A from XHL (packed hi|lo NCHW), B from WH/WL. 3-term MFMA: hihi + hilo + lohi.
__global__ __launch_bounds__(256) void gemm_mfma_x2(
    const unsigned int* __restrict__ XHL,
    const unsigned short* __restrict__ WH, const unsigned short* __restrict__ WL,
    float* __restrict__ C, const float* __restrict__ e0)
{
    __shared__ __align__(16) unsigned short Ah[64 * 40];
    __shared__ __align__(16) unsigned short Al[64 * 40];
    __shared__ __align__(16) unsigned short Bh[64 * 40];
    __shared__ __align__(16) unsigned short Bl[64 * 40];
    int m0 = blockIdx.y * 64, n0 = blockIdx.x * 64;
    int tid = threadIdx.x;
    int w = tid >> 6, l = tid & 63, l15 = l & 15, q = l >> 4;
    unsigned int aR[8];
    uint4 bhR, blR;
    int bn = tid >> 2, bk = (tid & 3) * 8;

    auto loadA = [&](int k0) {
        #pragma unroll
        for (int i = 0; i < 8; i++) {
            int idx = i * 256 + tid;
            int kl = idx & 31, ml = idx >> 5;
            int m = m0 + ml, k = k0 + kl;
            int b = m >> 10, oy = (m >> 5) & 31, ox = m & 31;
            int c = k >> 4, ky = (k >> 2) & 3, kx = k & 3;
            int iy = 2 * oy - 1 + ky, ix = 2 * ox - 1 + kx;
            unsigned int v = 0;
            if ((unsigned)iy < 64u && (unsigned)ix < 64u)
                v = XHL[(((long)b * 256 + c) * 64 + iy) * 64 + ix];
            aR[i] = v;
        }
    };
    auto storeA = [&]() {
        #pragma unroll
        for (int i = 0; i < 8; i++) {
            int idx = i * 256 + tid;
            int kl = idx & 31, ml = idx >> 5;
            Ah[ml * 40 + kl] = (unsigned short)(aR[i] & 0xffffu);
            Al[ml * 40 + kl] = (unsigned short)(aR[i] >> 16);
        }
    };
    auto loadB = [&](int k0) {
        bhR = *(const uint4*)(WH + (long)(n0 + bn) * 4096 + (k0 + bk));
        blR = *(const uint4*)(WL + (long)(n0 + bn) * 4096 + (k0 + bk));
    };

    f32x4 acc[4] = {};
    loadA(0); loadB(0);
    for (int k0 = 0; k0 < 4096; k0 += 32) {
        storeA();
        *(uint4*)(&Bh[bn * 40 + bk]) = bhR;
        *(uint4*)(&Bl[bn * 40 + bk]) = blR;
        __syncthreads();
        if (k0 + 32 < 4096) { loadA(k0 + 32); loadB(k0 + 32); }
        bf16x8 afh = *(const bf16x8*)(&Ah[(w * 16 + l15) * 40 + q * 8]);
        bf16x8 afl = *(const bf16x8*)(&Al[(w * 16 + l15) * 40 + q * 8]);
        #pragma unroll
        for (int j4 = 0; j4 < 4; j4++) {
            bf16x8 bfh = *(const bf16x8*)(&Bh[(j4 * 16 + l15) * 40 + q * 8]);
            bf16x8 bfl = *(const bf16x8*)(&Bl[(j4 * 16 + l15) * 40 + q * 8]);
            acc[j4] = __builtin_amdgcn_mfma_f32_16x16x32_bf16(afh, bfh, acc[j4], 0, 0, 0);
            acc[j4] = __builtin_amdgcn_mfma_f32_16x16x32_bf16(afh, bfl, acc[j4], 0, 0, 0);
            acc[j4] = __builtin_amdgcn_mfma_f32_16x16x32_bf16(afl, bfh, acc[j4], 0, 0, 0);
        }
        __syncthreads();
    }
    #pragma unroll
    for (int j4 = 0; j4 < 4; j4++) {
        int n = n0 + j4 * 16 + l15;
        #pragma unroll
        for (int r = 0; r < 4; r++) {
            int m = m0 + w * 16 + q * 4 + r;
            C[(long)m * 256 + n] = acc[j4][r] + e0[n];
        }
    }
}

// ---------------- fp32 GEMM (coarse/fine qkv) -> split bf16 planes for MFMA attention ----------
// C[m,n] = sum_k A[m,k]*B[n,k] + e0[n].  n<64 -> Q (x0.125, split hi/lo), n<128 -> K (split),
// else V -> transposed plain bf16 [bh][d][tok].
template<int EPI>
__global__ __launch_bounds__(256) void gemm_k(
    const float* __restrict__ A, const float* __restrict__ B,
    unsigned short* __restrict__ out, int K, int sAm, int sBn, const float* __restrict__ e0)
{
    __shared__ float As[16][68];
    __shared__ float Bs[16][68];
    int m0 = blockIdx.y * 64;
    int n0 = blockIdx.x * 64;
    int tid = threadIdx.x;
    int tx = tid & 15, ty = tid >> 4;
    int l4 = tid >> 2, kq = (tid & 3) * 4;
    float4 aR, bR;

    auto loadA = [&](int k0) { aR = *(const float4*)(A + (long)(m0 + l4) * sAm + (k0 + kq)); };
    auto loadB = [&](int k0) { bR = *(const float4*)(B + (long)(n0 + l4) * sBn + (k0 + kq)); };

    float acc[4][4] = {};
    loadA(0); loadB(0);
    for (int k0 = 0; k0 < K; k0 += 16) {
        As[kq + 0][l4] = aR.x; As[kq + 1][l4] = aR.y; As[kq + 2][l4] = aR.z; As[kq + 3][l4] = aR.w;
        Bs[kq + 0][l4] = bR.x; Bs[kq + 1][l4] = bR.y; Bs[kq + 2][l4] = bR.z; Bs[kq + 3][l4] = bR.w;
        __syncthreads();
        if (k0 + 16 < K) { loadA(k0 + 16); loadB(k0 + 16); }
        #pragma unroll
        for (int kk = 0; kk < 16; ++kk) {
            float4 av = *reinterpret_cast<const float4*>(&As[kk][ty * 4]);
            float4 bv = *reinterpret_cast<const float4*>(&Bs[kk][tx * 4]);
            float a[4] = {av.x, av.y, av.z, av.w};
            float b[4] = {bv.x, bv.y, bv.z, bv.w};
            #pragma unroll
            for (int i = 0; i < 4; i++)
                #pragma unroll
                for (int j = 0; j < 4; j++)
                    acc[i][j] += a[i] * b[j];
        }
        __syncthreads();
    }
    #pragma unroll
    for (int i = 0; i < 4; i++) {
        int m = m0 + ty * 4 + i;
        int bh, tok;
        if (EPI == 2) { int bi = m >> 12; int h = m & 3; tok = (m >> 2) & 1023; bh = bi * 4 + h; }
        else          { bh = m >> 10; tok = m & 1023; }
        #pragma unroll
        for (int j = 0; j < 4; j++) {
            int n = n0 + tx * 4 + j;
            float v = acc[i][j] + e0[n];
            if (n < 64) {
                v *= 0.125f;  // fold attention scale into Q
                unsigned short hb = f2bf(v);
                float fh = __uint_as_float(((unsigned int)hb) << 16);
                unsigned short lb = f2bf(v - fh);
                long p = (((long)bh << 10) + tok) * 64 + n;
                out[p] = hb; out[p + 2097152] = lb;
            } else if (n < 128) {
                unsigned short hb = f2bf(v);
                float fh = __uint_as_float(((unsigned int)hb) << 16);
                unsigned short lb = f2bf(v - fh);
                long p = (((long)bh << 10) + tok) * 64 + (n - 64);
                out[p + 4194304] = hb; out[p + 6291456] = lb;
            } else {
                out[8388608 + (((long)bh << 6) + (n - 128)) * 1024 + tok] = f2bf(v);
            }
        }
    }
}

// ---------------- bf16 MFMA GEMM (post-topk) ----------------
// AMODE==2 (up-conv): per-slot gather geometry is K-invariant -> hoist spatial base + validity;
// per-iter index math reduced to ci = ci0 + (k0>>2) and two shifts.
template<int EPI, int AMODE>
__global__ __launch_bounds__(256) void gemm_mfma(
    const float* __restrict__ A, const unsigned short* __restrict__ Bb, float* __restrict__ C,
    int K, long sAz, long sBz, int sAk, int sBn,
    const float* __restrict__ e0, const float* __restrict__ e1,
    void* __restrict__ ob, const int* __restrict__ flagp)
{
    __shared__ __align__(16) unsigned short Asb[64 * 40];
    __shared__ __align__(16) unsigned short Bsb[64 * 40];
    int z = blockIdx.z;
    if (AMODE == 0) A += (long)z * sAz;
    Bb += (long)z * sBz;
    int m0 = blockIdx.y * 64, n0 = blockIdx.x * 64;
    int tid = threadIdx.x;
    int w = tid >> 6, l = tid & 63;
    int l15 = l & 15, q = l >> 4;
    float aR[8];
    uint4 bR;

    int sbA[8], ci0A[8];
    if (AMODE != 0) {
        #pragma unroll
        for (int i = 0; i < 8; i++) {
            int idx = i * 256 + tid;
            int kl = idx & 31, ml = idx >> 5;
            int m = m0 + ml;
            int b = m >> 10, y = (m >> 5) & 31, x2 = m & 31;
            int j = kl & 3;
            int pa = z >> 1, pb = z & 1;
            int jy = j >> 1, jx = j & 1;
            int dy = (pa == 0) ? (jy ? -1 : 0) : (jy ? 1 : 0);
            int dx = (pb == 0) ? (jx ? -1 : 0) : (jx ? 1 : 0);
            int yy = y + dy, xx = x2 + dx;
            ci0A[i] = kl >> 2;
            sbA[i] = ((unsigned)yy < 32u && (unsigned)xx < 32u)
                     ? (b * 262144 + (yy * 32 + xx) * 64) : -1;
        }
    }

    auto loadA = [&](int k0) {
        if (AMODE == 0) {
            #pragma unroll
            for (int i = 0; i < 8; i++) {
                int idx = i * 256 + tid;
                int ml = idx & 63, kl = idx >> 6;
                aR[i] = A[(long)(k0 + kl) * sAk + (m0 + ml)];
            }
        } else {
            int cq = k0 >> 2;
            #pragma unroll
            for (int i = 0; i < 8; i++) {
                int ci = ci0A[i] + cq;
                aR[i] = (sbA[i] >= 0) ? A[sbA[i] + ((ci >> 6) << 16) + (ci & 63)] : 0.f;
            }
        }
    };
    auto storeA = [&]() {
        #pragma unroll
        for (int i = 0; i < 8; i++) {
            int idx = i * 256 + tid;
            int ml, kl;
            if (AMODE == 0) { ml = idx & 63; kl = idx >> 6; }
            else            { kl = idx & 31; ml = idx >> 5; }
            Asb[ml * 40 + kl] = f2bf(aR[i]);
        }
    };
    int bn = tid >> 2, bk = (tid & 3) * 8;
    auto loadB = [&](int k0) {
        bR = *(const uint4*)(Bb + (long)(n0 + bn) * sBn + (k0 + bk));
    };

    f32x4 acc[4] = {};
    loadA(0); loadB(0);
    for (int k0 = 0; k0 < K; k0 += 32) {
        storeA();
        *(uint4*)(&Bsb[bn * 40 + bk]) = bR;
        __syncthreads();
        if (k0 + 32 < K) { loadA(k0 + 32); loadB(k0 + 32); }
        bf16x8 af = *(const bf16x8*)(&Asb[(w * 16 + l15) * 40 + q * 8]);
        #pragma unroll
        for (int j4 = 0; j4 < 4; j4++) {
            bf16x8 bf = *(const bf16x8*)(&Bsb[(j4 * 16 + l15) * 40 + q * 8]);
            acc[j4] = __builtin_amdgcn_mfma_f32_16x16x32_bf16(af, bf, acc[j4], 0, 0, 0);
        }
        __syncthreads();
    }
    int oflag = (EPI == 5) ? *flagp : 0;
    #pragma unroll
    for (int j4 = 0; j4 < 4; j4++) {
        int n = n0 + j4 * 16 + l15;
        #pragma unroll
        for (int r = 0; r < 4; r++) {
            int m = m0 + w * 16 + q * 4 + r;
            float v = acc[j4][r];
            if (EPI == 4) {
                v += e0[n];
                int pa = z >> 1, pb = z & 1;
                int bi = m >> 10, y = (m >> 5) & 31, x2 = m & 31;
                C[(((long)bi * 256 + n) * 64 + (2 * y + pa)) * 64 + (2 * x2 + pb)] = v;
            } else {
                v = relu6(v * e0[n] + e1[n]);
                long oidx = (long)z * 1048576 + (long)n * 4096 + m;
                if (oflag) ((bf16*)ob)[oidx] = __float2bfloat16(v);
                else       ((float*)ob)[oidx] = v;
            }
        }
    }
}

// ---------------- MFMA attention: [bh=32][N=1024][D=64], scale folded into Q ----------------
// Planes (ushort offsets from P0): QH +0, QL +2097152, KH +4194304, KL +6291456, VT +8388608.
// QK^T: split-precision 3-term bf16x2 (fp32-class logits => topk-safe scores).
// PV:   plain bf16 (P normalized/bounded by 1; same error class as post-topk bf16 GEMMs).
// R9: __launch_bounds__(256, 2) — grid is 512 blocks = 2 blocks/CU = 2 waves/EU, so allow
// up to 256 VGPRs. R8's 64-VGPR cap spilled the prefetch registers to scratch
// (WRITE_SIZE 116 MB, +25% dur). Same 2-barrier register-prefetch pipeline otherwise.
template<bool SCORE>
__global__ __launch_bounds__(256, 2) void attn_mfma(
    const unsigned short* __restrict__ P0,
    float* __restrict__ O, float* __restrict__ PSCW)
{
    const unsigned short* QH = P0;
    const unsigned short* QL = P0 + 2097152;
    const unsigned short* KH = P0 + 4194304;
    const unsigned short* KL = P0 + 6291456;
    const unsigned short* VT = P0 + 8388608;
    __shared__ __align__(16) unsigned short Khs[64 * 72];
    __shared__ __align__(16) unsigned short Kls[64 * 72];
    __shared__ __align__(16) unsigned short Vs[64 * 72];
    __shared__ __align__(16) unsigned short Ps[4][16 * 72];   // per-wave private P tile
    int bh = blockIdx.y, rt = blockIdx.x;
    int tid = threadIdx.x;
    int w = tid >> 6, l = tid & 63, l15 = l & 15, q = l >> 4;

    // Q fragments: rows rt*64 + w*16 + l15, dims kk*32 + q*8 (+0..7). Loaded once.
    long qoff = (((long)bh << 10) + rt * 64 + w * 16 + l15) * 64 + q * 8;
    bf16x8 afh[2], afl[2];
    afh[0] = *(const bf16x8*)(QH + qoff);
    afh[1] = *(const bf16x8*)(QH + qoff + 32);
    afl[0] = *(const bf16x8*)(QL + qoff);
    afl[1] = *(const bf16x8*)(QL + qoff + 32);

    // staging geometry (t-invariant): 2 uint4 chunks per plane per thread
    int ldsKo[2], ldsVo[2];
    long gK[2], gV[2];
    #pragma unroll
    for (int i = 0; i < 2; i++) {
        int u = tid + i * 256;
        int tok = u >> 3, dp = (u & 7) * 8;
        ldsKo[i] = tok * 72 + dp;
        gK[i] = (((long)bh << 10) + tok) * 64 + dp;       // + t*4096 per tile
        ldsVo[i] = tok * 72 + dp;                          // d = tok, k0 = dp
        gV[i] = (((long)bh << 6) + tok) * 1024 + dp;       // + t*64 per tile
    }
    uint4 khR[2], klR[2], vR[2];
    auto loadK = [&](int t) {
        #pragma unroll
        for (int i = 0; i < 2; i++) {
            khR[i] = *(const uint4*)(KH + gK[i] + t * 4096);
            klR[i] = *(const uint4*)(KL + gK[i] + t * 4096);
        }
    };
    auto storeK = [&]() {
        #pragma unroll
        for (int i = 0; i < 2; i++) {
            *(uint4*)(Khs + ldsKo[i]) = khR[i];
            *(uint4*)(Kls + ldsKo[i]) = klR[i];
        }
    };
    auto loadV = [&](int t) {
        #pragma unroll
        for (int i = 0; i < 2; i++) vR[i] = *(const uint4*)(VT + gV[i] + t * 64);
    };
    auto storeV = [&]() {
        #pragma unroll
        for (int i = 0; i < 2; i++) *(uint4*)(Vs + ldsVo[i]) = vR[i];
    };

    float mr[4], lr[4];
    #pragma unroll
    for (int r = 0; r < 4; r++) { mr[r] = -1e30f; lr[r] = 0.f; }
    f32x4 o[4] = {};

    auto computeS = [&](f32x4* s) {
        #pragma unroll
        for (int kk = 0; kk < 2; kk++)
            #pragma unroll
            for (int j4 = 0; j4 < 4; j4++) {
                bf16x8 kh8 = *(const bf16x8*)(&Khs[(j4 * 16 + l15) * 72 + kk * 32 + q * 8]);
                bf16x8 kl8 = *(const bf16x8*)(&Kls[(j4 * 16 + l15) * 72 + kk * 32 + q * 8]);
                s[j4] = __builtin_amdgcn_mfma_f32_16x16x32_bf16(afh[kk], kh8, s[j4], 0, 0, 0);
                s[j4] = __builtin_amdgcn_mfma_f32_16x16x32_bf16(afh[kk], kl8, s[j4], 0, 0, 0);
                s[j4] = __builtin_amdgcn_mfma_f32_16x16x32_bf16(afl[kk], kh8, s[j4], 0, 0, 0);
            }
    };
    auto pv = [&]() {
        #pragma unroll
        for (int kk = 0; kk < 2; kk++) {
            bf16x8 ap = *(const bf16x8*)(&Ps[w][l15 * 72 + kk * 32 + q * 8]);
            #pragma unroll
            for (int j4 = 0; j4 < 4; j4++) {
                bf16x8 bv = *(const bf16x8*)(&Vs[(j4 * 16 + l15) * 72 + kk * 32 + q * 8]);
                o[j4] = __builtin_amdgcn_mfma_f32_16x16x32_bf16(ap, bv, o[j4], 0, 0, 0);
            }
        }
    };

    if (SCORE) {
        // ---- pass 1: row max + denom ----
        loadK(0);
        for (int t = 0; t < 16; ++t) {
            storeK();
            __syncthreads();
            if (t + 1 < 16) loadK(t + 1);
            f32x4 s[4] = {};
            computeS(s);
            #pragma unroll
            for (int r = 0; r < 4; r++) {
                float tm = fmaxf(fmaxf(s[0][r], s[1][r]), fmaxf(s[2][r], s[3][r]));
                #pragma unroll
                for (int off = 1; off < 16; off <<= 1) tm = fmaxf(tm, __shfl_xor(tm, off));
                float mn = fmaxf(mr[r], tm);
                float ss = __expf(s[0][r] - mn) + __expf(s[1][r] - mn)
                         + __expf(s[2][r] - mn) + __expf(s[3][r] - mn);
                #pragma unroll
                for (int off = 1; off < 16; off <<= 1) ss += __shfl_xor(ss, off);
                lr[r] = lr[r] * __expf(mr[r] - mn) + ss;
                mr[r] = mn;
            }
            __syncthreads();
        }
        float linv[4];
        #pragma unroll
        for (int r = 0; r < 4; r++) linv[r] = 1.f / lr[r];
        // ---- pass 2: normalized P, colsums, PV ----
        loadK(0); loadV(0);
        for (int t = 0; t < 16; ++t) {
            storeK(); storeV();
            __syncthreads();
            if (t + 1 < 16) { loadK(t + 1); loadV(t + 1); }
            f32x4 s[4] = {};
            computeS(s);
            float cs[4] = {0.f, 0.f, 0.f, 0.f};
            #pragma unroll
            for (int j4 = 0; j4 < 4; j4++)
                #pragma unroll
                for (int r = 0; r < 4; r++) {
                    float p = __expf(s[j4][r] - mr[r]) * linv[r];
                    cs[j4] += p;
                    Ps[w][(q * 4 + r) * 72 + j4 * 16 + l15] = f2bf(p);
                }
            #pragma unroll
            for (int j4 = 0; j4 < 4; j4++) {
                cs[j4] += __shfl_xor(cs[j4], 16);
                cs[j4] += __shfl_xor(cs[j4], 32);
            }
            if (q == 0) {
                long pb = (((long)(bh * 16 + rt) * 4 + w) << 10) + t * 64;
                #pragma unroll
                for (int j4 = 0; j4 < 4; j4++) PSCW[pb + j4 * 16 + l15] = cs[j4];
            }
            pv();
            __syncthreads();
        }
    } else {
        // ---- single-pass online-softmax flash ----
        loadK(0); loadV(0);
        for (int t = 0; t < 16; ++t) {
            storeK(); storeV();
            __syncthreads();
            if (t + 1 < 16) { loadK(t + 1); loadV(t + 1); }
            f32x4 s[4] = {};
            computeS(s);
            float corr[4];
            #pragma unroll
            for (int r = 0; r < 4; r++) {
                float tm = fmaxf(fmaxf(s[0][r], s[1][r]), fmaxf(s[2][r], s[3][r]));
                #pragma unroll
                for (int off = 1; off < 16; off <<= 1) tm = fmaxf(tm, __shfl_xor(tm, off));
                float mn = fmaxf(mr[r], tm);
                corr[r] = __expf(mr[r] - mn);
                mr[r] = mn;
            }
            float ssr[4] = {0.f, 0.f, 0.f, 0.f};
            #pragma unroll
            for (int j4 = 0; j4 < 4; j4++)
                #pragma unroll
                for (int r = 0; r < 4; r++) {
                    float p = __expf(s[j4][r] - mr[r]);
                    ssr[r] += p;
                    Ps[w][(q * 4 + r) * 72 + j4 * 16 + l15] = f2bf(p);
                }
            #pragma unroll
            for (int r = 0; r < 4; r++) {
                float ss = ssr[r];
                #pragma unroll
                for (int off = 1; off < 16; off <<= 1) ss += __shfl_xor(ss, off);
                lr[r] = lr[r] * corr[r] + ss;
            }
            #pragma unroll
            for (int j4 = 0; j4 < 4; j4++)
                #pragma unroll
                for (int r = 0; r < 4; r++) o[j4][r] *= corr[r];
            pv();
            __syncthreads();
        }
    }

    float fin[4];
    #pragma unroll
    for (int r = 0; r < 4; r++) fin[r] = SCORE ? 1.f : (1.f / lr[r]);
    long obase = (((long)bh << 10) + rt * 64 + w * 16 + q * 4) * 64;
    #pragma unroll
    for (int j4 = 0; j4 < 4; j4++)
        #pragma unroll
        for (int r = 0; r < 4; r++)
            O[obase + (long)r * 64 + j4 * 16 + l15] = o[j4][r] * fin[r];
}

// topk with fused colsum-partial reduction (replaces score_reduce + old topk)
__global__ __launch_bounds__(256) void topk_kernel(const float* __restrict__ PSCW, int* __restrict__ topk) {
    __shared__ float s[1024];
    int z = blockIdx.x; int tid = threadIdx.x;
    for (int i = tid; i < 1024; i += 256) {
        float v = 0.f;
        for (int rw = 0; rw < 64; rw++) v += PSCW[(((long)z * 64 + rw) << 10) + i];
        s[i] = (v == v) ? v : -INFINITY;
    }
    __syncthreads();
    for (int i = tid; i < 1024; i += 256) {
        float si = s[i]; int r = 0;
        for (int j = 0; j < 1024; j++) {
            float sj = s[j];
            r += (sj > si) || (sj == si && j < i);
        }
        if (r < 256) topk[z * 256 + r] = i;
    }
}

__global__ __launch_bounds__(256) void gather_tokf_kernel(const float* __restrict__ coarse,
                                                          const int* __restrict__ topk,
                                                          float* __restrict__ tokf) {
    long idx = (long)blockIdx.x * 256 + threadIdx.x;
    int d = (int)(idx & 63); int t = (int)((idx >> 6) & 3);
    int j = (int)((idx >> 8) & 255); int bh = (int)(idx >> 16);
    int p = topk[bh * 256 + j] & 1023;
    int py = p >> 5, px = p & 31;
    int dy = t >> 1, dx = t & 1;
    int b = bh >> 2, h = bh & 3;
    tokf[idx] = coarse[(((long)b * 256 + h * 64 + d) * 64 + (2 * py + dy)) * 64 + (2 * px + dx)];
}

__global__ __launch_bounds__(256) void scatter_add_kernel(float* __restrict__ coarse,
                                                          const int* __restrict__ topk,
                                                          const float* __restrict__ outf) {
    long idx = (long)blockIdx.x * 256 + threadIdx.x;
    int d = (int)(idx & 63); int t = (int)((idx >> 6) & 3);
    int j = (int)((idx >> 8) & 255); int bh = (int)(idx >> 16);
    int p = topk[bh * 256 + j] & 1023;
    int py = p >> 5, px = p & 31;
    int dy = t >> 1, dx = t & 1;
    int b = bh >> 2, h = bh & 3;
    coarse[(((long)b * 256 + h * 64 + d) * 64 + (2 * py + dy)) * 64 + (2 * px + dx)] += outf[idx];
}

__global__ __launch_bounds__(64) void dw_bn_relu6_kernel(const float* __restrict__ y, const float* __restrict__ w9,
                                                         const float* __restrict__ s1, const float* __restrict__ t1,
                                                         float* __restrict__ out) {
    int gid = blockIdx.x;
    int row = gid & 63; int bc = gid >> 6; int c = bc & 255;
    int x = threadIdx.x;
    const float* base = y + (long)bc * 4096;
    float acc = 0.f;
    #pragma unroll
    for (int ky = 0; ky < 3; ky++) {
        int yy = row + ky - 1;
        if (yy < 0 || yy >= 64) continue;
        #pragma unroll
        for (int kx = 0; kx < 3; kx++) {
            int xx = x + kx - 1;
            if (xx < 0 || xx >= 64) continue;
            acc += base[yy * 64 + xx] * w9[c * 9 + ky * 3 + kx];
        }
    }
    out[(long)gid * 64 + x] = relu6(acc * s1[c] + t1[c]);
}

// ---------------- launch ----------------
extern "C" void kernel_launch(void* const* d_in, const int* in_sizes, int n_in,
                              void* d_out, int out_size, void* d_ws, size_t ws_size,
                              hipStream_t stream) {
    if (ws_size < (size_t)WS_FLOATS * 4) return;

    const void* x      = d_in[0];
    const void* down_w = d_in[1];
    const void* down_b = d_in[2];
    const void* up_w   = d_in[3];
    const void* up_b   = d_in[4];
    const void* wqkv_c = d_in[5];
    const void* bqkv_c = d_in[6];
    const void* wqkv_f = d_in[7];
    const void* bqkv_f = d_in[8];
    const void* dw_w   = d_in[9];
    const void* bn1_g  = d_in[10];
    const void* bn1_b  = d_in[11];
    const void* bn1_m  = d_in[12];
    const void* bn1_v  = d_in[13];
    const void* pw_w   = d_in[14];
    const void* bn2_g  = d_in[15];
    const void* bn2_b  = d_in[16];
    const void* bn2_m  = d_in[17];
    const void* bn2_v  = d_in[18];

    float* ws = (float*)d_ws;
    int* flagp = (int*)(ws + OFF_FLAG);
    dim3 blk(256);

    hipMemsetAsync(flagp, 0, sizeof(int), stream);
    detect_kernel<<<1, blk, 0, stream>>>(x, flagp);

    // split x and down_w into bf16 hi/lo
    split_pack_kernel<<<32768, blk, 0, stream>>>(x, (unsigned int*)(ws + OFF_XHL), 8388608, flagp);
    split_kernel<<<4096, blk, 0, stream>>>(down_w, (unsigned short*)(ws + OFF_DOWNW),
                                           (unsigned short*)(ws + OFF_DOWNWL), 1048576, flagp);
    prep_misc_kernel<<<367, blk, 0, stream>>>(down_b, up_b, bqkv_c, bqkv_f, dw_w, wqkv_c, wqkv_f, pw_w,
                                              bn1_g, bn1_b, bn1_m, bn1_v, bn2_g, bn2_b, bn2_m, bn2_v,
                                              ws, flagp);
    prep_up_kernel<<<4096, blk, 0, stream>>>(up_w, (unsigned short*)(ws + OFF_UPW4), flagp);

    // down conv (bf16x2 MFMA, topk-safe): M=8192, N=256, K=4096 -> xd NHWC
    gemm_mfma_x2<<<dim3(4, 128, 1), blk, 0, stream>>>((const unsigned int*)(ws + OFF_XHL),
        (const unsigned short*)(ws + OFF_DOWNW), (const unsigned short*)(ws + OFF_DOWNWL),
        ws + OFF_XDHWC, ws + OFF_DOWNB);

    // coarse qkv: M=32768, N=192, K=64 -> split bf16 planes (Q scaled)
    gemm_k<2><<<dim3(3, 512, 1), blk, 0, stream>>>(ws + OFF_XDHWC, ws + OFF_WQKVC,
        (unsigned short*)(ws + OFF_QH), 64, 64, 64, ws + OFF_BQKVC);

    // coarse MFMA attention (two-pass, + per-wave colsum partials) -> OUTC, PSCW
    attn_mfma<true><<<dim3(16, 32), blk, 0, stream>>>((const unsigned short*)(ws + OFF_QH),
        ws + OFF_OUTC, ws + OFF_PSCW);
    topk_kernel<<<32, blk, 0, stream>>>(ws + OFF_PSCW, (int*)(ws + OFF_TOPK));

    // up conv (bf16 MFMA, post-topk): M=8192, N=256, K=1024, z=cls -> coarse NCHW (overwrites XHL/PSCW)
    gemm_mfma<4, 2><<<dim3(4, 128, 4), blk, 0, stream>>>(ws + OFF_OUTC, (unsigned short*)(ws + OFF_UPW4),
        ws + OFF_COARSE, 1024, 0, 262144, 0, 1024, ws + OFF_UPB, nullptr, nullptr, flagp);

    // fine attention
    gather_tokf_kernel<<<8192, blk, 0, stream>>>(ws + OFF_COARSE, (const int*)(ws + OFF_TOPK), ws + OFF_XDHWC);
    gemm_k<3><<<dim3(3, 512, 1), blk, 0, stream>>>(ws + OFF_XDHWC, ws + OFF_WQKVF,
        (unsigned short*)(ws + OFF_QH), 64, 64, 64, ws + OFF_BQKVF);
    attn_mfma<false><<<dim3(16, 32), blk, 0, stream>>>((const unsigned short*)(ws + OFF_QH),
        ws + OFF_OUTC, nullptr);
    scatter_add_kernel<<<8192, blk, 0, stream>>>(ws + OFF_COARSE, (const int*)(ws + OFF_TOPK), ws + OFF_OUTC);

    // depthwise + bn1 + relu6 -> T1
    dw_bn_relu6_kernel<<<131072, dim3(64), 0, stream>>>(ws + OFF_COARSE, ws + OFF_DWW,
        ws + OFF_BN1S, ws + OFF_BN1T, ws + OFF_T1);

    // pointwise + bn2 + relu6 (bf16 MFMA) -> d_out: M=4096, N=256, K=256, z=batch
    gemm_mfma<5, 0><<<dim3(4, 64, 8), blk, 0, stream>>>(ws + OFF_T1, (unsigned short*)(ws + OFF_PWW),
        nullptr, 256, 1048576, 0, 4096, 256, ws + OFF_BN2S, ws + OFF_BN2T, d_out, flagp);
}

// Round 10
// 774.840 us; speedup vs baseline: 1.0922x; 1.0922x over previous
//
#include <hip/hip_runtime.h>
#include <hip/hip_bf16.h>

typedef __hip_bfloat16 bf16;
typedef __bf16 bf16x8 __attribute__((ext_vector_type(8)));
typedef float f32x4 __attribute__((ext_vector_type(4)));

// B=8, C=256, H=W=64, nh=4, HD=64, coarse tokens N=1024 (32x32), kf=256, fine tokens 1024.
// fp32 in/out (auto-detected). Top-k-critical paths (down-conv, attention QK^T) use bf16x2
// split-precision MFMA (error ~2^-17, fp32-class => tie-safe); PV + post-topk GEMMs plain bf16 MFMA.

// ---------------- workspace layout (float offsets) ----------------
#define OFF_XDHWC    0L
#define OFF_QH       2097152L     // 5 planes (ushort units vs this base):
                                  //   QH +0, QL +2097152, KH +4194304, KL +6291456, VT +8388608
#define OFF_T1       0L           // overlay on trunk
#define OFF_OUTC     8388608L
#define OFF_COARSE   10485760L    // XHL (packed hi|lo x) first, then PSCW, then coarse NCHW -> y
#define OFF_XHL      10485760L    // 8,388,608 uint (hi|lo packed bf16 of x, NCHW)
#define OFF_PSCW     10485760L    // 2M floats: per-(bh,rt,wave) colsum partials (XHL dead by then)
#define OFF_SCORE    19398656L
#define OFF_TOPK     19431424L
#define OFF_DOWNW    19439616L    // WH bf16 [co][k] (1M ushort); WL at +524288 floats
#define OFF_DOWNWL   19963904L
#define OFF_UPW4     20488192L    // bf16 (ushort) [cls][co][k]
#define OFF_WQKVC    21536768L
#define OFF_BQKVC    21549056L
#define OFF_WQKVF    21549248L
#define OFF_BQKVF    21561536L
#define OFF_PWW      21561728L    // bf16 (ushort) [co][ci]
#define OFF_DWW      21627264L
#define OFF_BN1S     21629568L
#define OFF_BN1T     21629824L
#define OFF_BN2S     21630080L
#define OFF_BN2T     21630336L
#define OFF_DOWNB    21630592L
#define OFF_UPB      21630848L
#define OFF_FLAG     21631104L    // 1 int: 1 = bf16 world, 0 = fp32 world (default via memset)
#define WS_FLOATS    21631360L

__device__ __forceinline__ float relu6(float v) { return v < 0.f ? 0.f : (v > 6.f ? 6.f : v); }

__device__ __forceinline__ float ldin(const void* p, long i, int flag) {
    return flag ? __bfloat162float(((const bf16*)p)[i]) : ((const float*)p)[i];
}

// fp32 -> bf16 bits, round-to-nearest-even
__device__ __forceinline__ unsigned short f2bf(float f) {
    unsigned int b = __float_as_uint(f);
    b += 0x7FFFu + ((b >> 16) & 1u);
    return (unsigned short)(b >> 16);
}

// ---------------- dtype detector ----------------
__global__ __launch_bounds__(256) void detect_kernel(const void* __restrict__ x, int* __restrict__ flag) {
    __shared__ int cnt[256];
    int tid = threadIdx.x;
    int c = 0;
    for (int i = tid; i < 4096; i += 256) {
        long idx = (long)i * 2047;
        float v = __bfloat162float(((const bf16*)x)[idx]);
        float a = fabsf(v);
        if (isfinite(v) && a > 1e-8f && a < 100.f) c++;
    }
    cnt[tid] = c; __syncthreads();
    for (int s = 128; s > 0; s >>= 1) { if (tid < s) cnt[tid] += cnt[tid + s]; __syncthreads(); }
    if (tid == 0 && cnt[0] >= 3686) *flag = 1;
}

// ---------------- prep kernels (dual-dtype) ----------------
// split to packed hi|lo uint (x): low16 = bf16(v), high16 = bf16(v - hi)
__global__ __launch_bounds__(256) void split_pack_kernel(const void* __restrict__ in, unsigned int* __restrict__ out,
                                                         int n, const int* __restrict__ flagp) {
    int flag = *flagp;
    int i = blockIdx.x * 256 + threadIdx.x;
    if (i < n) {
        float v = ldin(in, i, flag);
        unsigned short h = f2bf(v);
        float fh = __uint_as_float(((unsigned int)h) << 16);
        unsigned short l = f2bf(v - fh);
        out[i] = (unsigned int)h | ((unsigned int)l << 16);
    }
}

// split to separate hi/lo planes (down_w, layout [co][k] is identity with input flat layout)
__global__ __launch_bounds__(256) void split_kernel(const void* __restrict__ in,
                                                    unsigned short* __restrict__ hi, unsigned short* __restrict__ lo,
                                                    int n, const int* __restrict__ flagp) {
    int flag = *flagp;
    int i = blockIdx.x * 256 + threadIdx.x;
    if (i < n) {
        float v = ldin(in, i, flag);
        unsigned short h = f2bf(v);
        float fh = __uint_as_float(((unsigned int)h) << 16);
        hi[i] = h;
        lo[i] = f2bf(v - fh);
    }
}

// up_w [ci,co,4,4] -> W4 bf16 [cls][co][ci*4+j]
__global__ __launch_bounds__(256) void prep_up_kernel(const void* __restrict__ w, unsigned short* __restrict__ W4,
                                                      const int* __restrict__ flagp) {
    int flag = *flagp;
    int idx = blockIdx.x * 256 + threadIdx.x;
    int cls = idx >> 18; int rem = idx & 262143;
    int co = rem >> 10; int q = rem & 1023;
    int ci = q >> 2; int j = q & 3;
    int pa = cls >> 1, pb = cls & 1;
    int jy = j >> 1, jx = j & 1;
    int ky = (pa == 0) ? (jy ? 3 : 1) : (jy ? 0 : 2);
    int kx = (pb == 0) ? (jx ? 3 : 1) : (jx ? 0 : 2);
    W4[idx] = f2bf(ldin(w, (((long)ci * 256 + co) * 4 + ky) * 4 + kx, flag));
}

// fused small-tensor prep: tqkv_c, tqkv_f, dw_w, biases, bn1/bn2, pw_w (replaces 10 launches)
__global__ __launch_bounds__(256) void prep_misc_kernel(
    const void* __restrict__ down_b, const void* __restrict__ up_b,
    const void* __restrict__ bqkv_c, const void* __restrict__ bqkv_f,
    const void* __restrict__ dw_w, const void* __restrict__ wqkv_c,
    const void* __restrict__ wqkv_f, const void* __restrict__ pw_w,
    const void* __restrict__ bn1_g, const void* __restrict__ bn1_b,
    const void* __restrict__ bn1_m, const void* __restrict__ bn1_v,
    const void* __restrict__ bn2_g, const void* __restrict__ bn2_b,
    const void* __restrict__ bn2_m, const void* __restrict__ bn2_v,
    float* __restrict__ ws, const int* __restrict__ flagp)
{
    int flag = *flagp;
    int bid = blockIdx.x, tid = threadIdx.x;
    if (bid < 48) {                        // wqkv_c transpose -> [j][d]
        int idx = bid * 256 + tid;
        int j = idx >> 6, d = idx & 63;
        ws[OFF_WQKVC + idx] = ldin(wqkv_c, d * 192 + j, flag);
    } else if (bid < 96) {                 // wqkv_f transpose
        int idx = (bid - 48) * 256 + tid;
        int j = idx >> 6, d = idx & 63;
        ws[OFF_WQKVF + idx] = ldin(wqkv_f, d * 192 + j, flag);
    } else if (bid < 105) {                // dw_w cvt (2304)
        int i = (bid - 96) * 256 + tid;
        if (i < 2304) ws[OFF_DWW + i] = ldin(dw_w, i, flag);
    } else if (bid == 105) {
        ws[OFF_DOWNB + tid] = ldin(down_b, tid, flag);
    } else if (bid == 106) {
        ws[OFF_UPB + tid] = ldin(up_b, tid, flag);
    } else if (bid == 107) {
        if (tid < 192) ws[OFF_BQKVC + tid] = ldin(bqkv_c, tid, flag);
    } else if (bid == 108) {
        if (tid < 192) ws[OFF_BQKVF + tid] = ldin(bqkv_f, tid, flag);
    } else if (bid == 109) {               // bn1 prep
        float gv = ldin(bn1_g, tid, flag), bv = ldin(bn1_b, tid, flag);
        float mv = ldin(bn1_m, tid, flag), vv = ldin(bn1_v, tid, flag);
        float inv = gv / sqrtf(vv + 1e-5f);
        ws[OFF_BN1S + tid] = inv; ws[OFF_BN1T + tid] = bv - mv * inv;
    } else if (bid == 110) {               // bn2 prep
        float gv = ldin(bn2_g, tid, flag), bv = ldin(bn2_b, tid, flag);
        float mv = ldin(bn2_m, tid, flag), vv = ldin(bn2_v, tid, flag);
        float inv = gv / sqrtf(vv + 1e-5f);
        ws[OFF_BN2S + tid] = inv; ws[OFF_BN2T + tid] = bv - mv * inv;
    } else {                               // pw_w -> bf16 (65536), blocks 111..366
        int i = (bid - 111) * 256 + tid;
        ((unsigned short*)(ws + OFF_PWW))[i] = f2bf(ldin(pw_w, i, flag));
    }
}

// ---------------- bf16x2 split-precision MFMA down-conv (top-k-safe) ----------------
// R1-exact structure (best measured: 122.9us): 64x64 tile, BK=32, grid 4x128.
// C[m,n] = conv; m=(b,oy,ox) M=8192, n=co N=256, k=(ci,ky,kx) K=4096.
// A from XHL (packed hi|lo NCHW), B from WH/WL. 3-term MFMA: hihi + hilo + lohi.
__global__ __launch_bounds__(256) void gemm_mfma_x2(
    const unsigned int* __restrict__ XHL,
    const unsigned short* __restrict__ WH, const unsigned short* __restrict__ WL,
    float* __restrict__ C, const float* __restrict__ e0)
{
    __shared__ __align__(16) unsigned short Ah[64 * 40];
    __shared__ __align__(16) unsigned short Al[64 * 40];
    __shared__ __align__(16) unsigned short Bh[64 * 40];
    __shared__ __align__(16) unsigned short Bl[64 * 40];
    int m0 = blockIdx.y * 64, n0 = blockIdx.x * 64;
    int tid = threadIdx.x;
    int w = tid >> 6, l = tid & 63, l15 = l & 15, q = l >> 4;
    unsigned int aR[8];
    uint4 bhR, blR;
    int bn = tid >> 2, bk = (tid & 3) * 8;

    auto loadA = [&](int k0) {
        #pragma unroll
        for (int i = 0; i < 8; i++) {
            int idx = i * 256 + tid;
            int kl = idx & 31, ml = idx >> 5;
            int m = m0 + ml, k = k0 + kl;
            int b = m >> 10, oy = (m >> 5) & 31, ox = m & 31;
            int c = k >> 4, ky = (k >> 2) & 3, kx = k & 3;
            int iy = 2 * oy - 1 + ky, ix = 2 * ox - 1 + kx;
            unsigned int v = 0;
            if ((unsigned)iy < 64u && (unsigned)ix < 64u)
                v = XHL[(((long)b * 256 + c) * 64 + iy) * 64 + ix];
            aR[i] = v;
        }
    };
    auto storeA = [&]() {
        #pragma unroll
        for (int i = 0; i < 8; i++) {
            int idx = i * 256 + tid;
            int kl = idx & 31, ml = idx >> 5;
            Ah[ml * 40 + kl] = (unsigned short)(aR[i] & 0xffffu);
            Al[ml * 40 + kl] = (unsigned short)(aR[i] >> 16);
        }
    };
    auto loadB = [&](int k0) {
        bhR = *(const uint4*)(WH + (long)(n0 + bn) * 4096 + (k0 + bk));
        blR = *(const uint4*)(WL + (long)(n0 + bn) * 4096 + (k0 + bk));
    };

    f32x4 acc[4] = {};
    loadA(0); loadB(0);
    for (int k0 = 0; k0 < 4096; k0 += 32) {
        storeA();
        *(uint4*)(&Bh[bn * 40 + bk]) = bhR;
        *(uint4*)(&Bl[bn * 40 + bk]) = blR;
        __syncthreads();
        if (k0 + 32 < 4096) { loadA(k0 + 32); loadB(k0 + 32); }
        bf16x8 afh = *(const bf16x8*)(&Ah[(w * 16 + l15) * 40 + q * 8]);
        bf16x8 afl = *(const bf16x8*)(&Al[(w * 16 + l15) * 40 + q * 8]);
        #pragma unroll
        for (int j4 = 0; j4 < 4; j4++) {
            bf16x8 bfh = *(const bf16x8*)(&Bh[(j4 * 16 + l15) * 40 + q * 8]);
            bf16x8 bfl = *(const bf16x8*)(&Bl[(j4 * 16 + l15) * 40 + q * 8]);
            acc[j4] = __builtin_amdgcn_mfma_f32_16x16x32_bf16(afh, bfh, acc[j4], 0, 0, 0);
            acc[j4] = __builtin_amdgcn_mfma_f32_16x16x32_bf16(afh, bfl, acc[j4], 0, 0, 0);
            acc[j4] = __builtin_amdgcn_mfma_f32_16x16x32_bf16(afl, bfh, acc[j4], 0, 0, 0);
        }
        __syncthreads();
    }
    #pragma unroll
    for (int j4 = 0; j4 < 4; j4++) {
        int n = n0 + j4 * 16 + l15;
        #pragma unroll
        for (int r = 0; r < 4; r++) {
            int m = m0 + w * 16 + q * 4 + r;
            C[(long)m * 256 + n] = acc[j4][r] + e0[n];
        }
    }
}

// ---------------- fp32 GEMM (coarse/fine qkv) -> split bf16 planes for MFMA attention ----------
// C[m,n] = sum_k A[m,k]*B[n,k] + e0[n].  n<64 -> Q (x0.125, split hi/lo), n<128 -> K (split),
// else V -> transposed plain bf16 [bh][d][tok].
template<int EPI>
__global__ __launch_bounds__(256) void gemm_k(
    const float* __restrict__ A, const float* __restrict__ B,
    unsigned short* __restrict__ out, int K, int sAm, int sBn, const float* __restrict__ e0)
{
    __shared__ float As[16][68];
    __shared__ float Bs[16][68];
    int m0 = blockIdx.y * 64;
    int n0 = blockIdx.x * 64;
    int tid = threadIdx.x;
    int tx = tid & 15, ty = tid >> 4;
    int l4 = tid >> 2, kq = (tid & 3) * 4;
    float4 aR, bR;

    auto loadA = [&](int k0) { aR = *(const float4*)(A + (long)(m0 + l4) * sAm + (k0 + kq)); };
    auto loadB = [&](int k0) { bR = *(const float4*)(B + (long)(n0 + l4) * sBn + (k0 + kq)); };

    float acc[4][4] = {};
    loadA(0); loadB(0);
    for (int k0 = 0; k0 < K; k0 += 16) {
        As[kq + 0][l4] = aR.x; As[kq + 1][l4] = aR.y; As[kq + 2][l4] = aR.z; As[kq + 3][l4] = aR.w;
        Bs[kq + 0][l4] = bR.x; Bs[kq + 1][l4] = bR.y; Bs[kq + 2][l4] = bR.z; Bs[kq + 3][l4] = bR.w;
        __syncthreads();
        if (k0 + 16 < K) { loadA(k0 + 16); loadB(k0 + 16); }
        #pragma unroll
        for (int kk = 0; kk < 16; ++kk) {
            float4 av = *reinterpret_cast<const float4*>(&As[kk][ty * 4]);
            float4 bv = *reinterpret_cast<const float4*>(&Bs[kk][tx * 4]);
            float a[4] = {av.x, av.y, av.z, av.w};
            float b[4] = {bv.x, bv.y, bv.z, bv.w};
            #pragma unroll
            for (int i = 0; i < 4; i++)
                #pragma unroll
                for (int j = 0; j < 4; j++)
                    acc[i][j] += a[i] * b[j];
        }
        __syncthreads();
    }
    #pragma unroll
    for (int i = 0; i < 4; i++) {
        int m = m0 + ty * 4 + i;
        int bh, tok;
        if (EPI == 2) { int bi = m >> 12; int h = m & 3; tok = (m >> 2) & 1023; bh = bi * 4 + h; }
        else          { bh = m >> 10; tok = m & 1023; }
        #pragma unroll
        for (int j = 0; j < 4; j++) {
            int n = n0 + tx * 4 + j;
            float v = acc[i][j] + e0[n];
            if (n < 64) {
                v *= 0.125f;  // fold attention scale into Q
                unsigned short hb = f2bf(v);
                float fh = __uint_as_float(((unsigned int)hb) << 16);
                unsigned short lb = f2bf(v - fh);
                long p = (((long)bh << 10) + tok) * 64 + n;
                out[p] = hb; out[p + 2097152] = lb;
            } else if (n < 128) {
                unsigned short hb = f2bf(v);
                float fh = __uint_as_float(((unsigned int)hb) << 16);
                unsigned short lb = f2bf(v - fh);
                long p = (((long)bh << 10) + tok) * 64 + (n - 64);
                out[p + 4194304] = hb; out[p + 6291456] = lb;
            } else {
                out[8388608 + (((long)bh << 6) + (n - 128)) * 1024 + tok] = f2bf(v);
            }
        }
    }
}

// ---------------- bf16 MFMA GEMM (post-topk) ----------------
// AMODE==2 (up-conv): per-slot gather geometry is K-invariant -> hoist spatial base + validity;
// per-iter index math reduced to ci = ci0 + (k0>>2) and two shifts.
template<int EPI, int AMODE>
__global__ __launch_bounds__(256) void gemm_mfma(
    const float* __restrict__ A, const unsigned short* __restrict__ Bb, float* __restrict__ C,
    int K, long sAz, long sBz, int sAk, int sBn,
    const float* __restrict__ e0, const float* __restrict__ e1,
    void* __restrict__ ob, const int* __restrict__ flagp)
{
    __shared__ __align__(16) unsigned short Asb[64 * 40];
    __shared__ __align__(16) unsigned short Bsb[64 * 40];
    int z = blockIdx.z;
    if (AMODE == 0) A += (long)z * sAz;
    Bb += (long)z * sBz;
    int m0 = blockIdx.y * 64, n0 = blockIdx.x * 64;
    int tid = threadIdx.x;
    int w = tid >> 6, l = tid & 63;
    int l15 = l & 15, q = l >> 4;
    float aR[8];
    uint4 bR;

    int sbA[8], ci0A[8];
    if (AMODE != 0) {
        #pragma unroll
        for (int i = 0; i < 8; i++) {
            int idx = i * 256 + tid;
            int kl = idx & 31, ml = idx >> 5;
            int m = m0 + ml;
            int b = m >> 10, y = (m >> 5) & 31, x2 = m & 31;
            int j = kl & 3;
            int pa = z >> 1, pb = z & 1;
            int jy = j >> 1, jx = j & 1;
            int dy = (pa == 0) ? (jy ? -1 : 0) : (jy ? 1 : 0);
            int dx = (pb == 0) ? (jx ? -1 : 0) : (jx ? 1 : 0);
            int yy = y + dy, xx = x2 + dx;
            ci0A[i] = kl >> 2;
            sbA[i] = ((unsigned)yy < 32u && (unsigned)xx < 32u)
                     ? (b * 262144 + (yy * 32 + xx) * 64) : -1;
        }
    }

    auto loadA = [&](int k0) {
        if (AMODE == 0) {
            #pragma unroll
            for (int i = 0; i < 8; i++) {
                int idx = i * 256 + tid;
                int ml = idx & 63, kl = idx >> 6;
                aR[i] = A[(long)(k0 + kl) * sAk + (m0 + ml)];
            }
        } else {
            int cq = k0 >> 2;
            #pragma unroll
            for (int i = 0; i < 8; i++) {
                int ci = ci0A[i] + cq;
                aR[i] = (sbA[i] >= 0) ? A[sbA[i] + ((ci >> 6) << 16) + (ci & 63)] : 0.f;
            }
        }
    };
    auto storeA = [&]() {
        #pragma unroll
        for (int i = 0; i < 8; i++) {
            int idx = i * 256 + tid;
            int ml, kl;
            if (AMODE == 0) { ml = idx & 63; kl = idx >> 6; }
            else            { kl = idx & 31; ml = idx >> 5; }
            Asb[ml * 40 + kl] = f2bf(aR[i]);
        }
    };
    int bn = tid >> 2, bk = (tid & 3) * 8;
    auto loadB = [&](int k0) {
        bR = *(const uint4*)(Bb + (long)(n0 + bn) * sBn + (k0 + bk));
    };

    f32x4 acc[4] = {};
    loadA(0); loadB(0);
    for (int k0 = 0; k0 < K; k0 += 32) {
        storeA();
        *(uint4*)(&Bsb[bn * 40 + bk]) = bR;
        __syncthreads();
        if (k0 + 32 < K) { loadA(k0 + 32); loadB(k0 + 32); }
        bf16x8 af = *(const bf16x8*)(&Asb[(w * 16 + l15) * 40 + q * 8]);
        #pragma unroll
        for (int j4 = 0; j4 < 4; j4++) {
            bf16x8 bf = *(const bf16x8*)(&Bsb[(j4 * 16 + l15) * 40 + q * 8]);
            acc[j4] = __builtin_amdgcn_mfma_f32_16x16x32_bf16(af, bf, acc[j4], 0, 0, 0);
        }
        __syncthreads();
    }
    int oflag = (EPI == 5) ? *flagp : 0;
    #pragma unroll
    for (int j4 = 0; j4 < 4; j4++) {
        int n = n0 + j4 * 16 + l15;
        #pragma unroll
        for (int r = 0; r < 4; r++) {
            int m = m0 + w * 16 + q * 4 + r;
            float v = acc[j4][r];
            if (EPI == 4) {
                v += e0[n];
                int pa = z >> 1, pb = z & 1;
                int bi = m >> 10, y = (m >> 5) & 31, x2 = m & 31;
                C[(((long)bi * 256 + n) * 64 + (2 * y + pa)) * 64 + (2 * x2 + pb)] = v;
            } else {
                v = relu6(v * e0[n] + e1[n]);
                long oidx = (long)z * 1048576 + (long)n * 4096 + m;
                if (oflag) ((bf16*)ob)[oidx] = __float2bfloat16(v);
                else       ((float*)ob)[oidx] = v;
            }
        }
    }
}

// ---------------- MFMA attention: [bh=32][N=1024][D=64], scale folded into Q ----------------
// Planes (ushort offsets from P0): QH +0, QL +2097152, KH +4194304, KL +6291456, VT +8388608.
// QK^T: split-precision 3-term bf16x2 (fp32-class logits => topk-safe scores).
// PV:   plain bf16 (P normalized/bounded by 1; same error class as post-topk bf16 GEMMs).
// R10: reverted to the R1 3-barrier staging loop — the 2-barrier register-prefetch variant
// spilled to scratch (VGPR cap 64, WRITE_SIZE 116 MB, +30us/dispatch in R8/R9).
template<bool SCORE>
__global__ __launch_bounds__(256) void attn_mfma(
    const unsigned short* __restrict__ P0,
    float* __restrict__ O, float* __restrict__ PSCW)
{
    const unsigned short* QH = P0;
    const unsigned short* QL = P0 + 2097152;
    const unsigned short* KH = P0 + 4194304;
    const unsigned short* KL = P0 + 6291456;
    const unsigned short* VT = P0 + 8388608;
    __shared__ __align__(16) unsigned short Khs[64 * 72];
    __shared__ __align__(16) unsigned short Kls[64 * 72];
    __shared__ __align__(16) unsigned short Vs[64 * 72];
    __shared__ __align__(16) unsigned short Ps[4][16 * 72];   // per-wave private P tile
    int bh = blockIdx.y, rt = blockIdx.x;
    int tid = threadIdx.x;
    int w = tid >> 6, l = tid & 63, l15 = l & 15, q = l >> 4;

    // Q fragments: rows rt*64 + w*16 + l15, dims kk*32 + q*8 (+0..7). Loaded once.
    long qoff = (((long)bh << 10) + rt * 64 + w * 16 + l15) * 64 + q * 8;
    bf16x8 afh[2], afl[2];
    afh[0] = *(const bf16x8*)(QH + qoff);
    afh[1] = *(const bf16x8*)(QH + qoff + 32);
    afl[0] = *(const bf16x8*)(QL + qoff);
    afl[1] = *(const bf16x8*)(QL + qoff + 32);

    float mr[4], lr[4];
    #pragma unroll
    for (int r = 0; r < 4; r++) { mr[r] = -1e30f; lr[r] = 0.f; }
    f32x4 o[4] = {};

    auto stageK = [&](int t) {
        #pragma unroll
        for (int i = 0; i < 2; i++) {
            int u = tid + i * 256;
            int tok = u >> 3, dp = (u & 7) * 8;
            long g = (((long)bh << 10) + t * 64 + tok) * 64 + dp;
            *(uint4*)(Khs + tok * 72 + dp) = *(const uint4*)(KH + g);
            *(uint4*)(Kls + tok * 72 + dp) = *(const uint4*)(KL + g);
        }
    };
    auto stageV = [&](int t) {
        #pragma unroll
        for (int i = 0; i < 2; i++) {
            int u = tid + i * 256;
            int d = u >> 3, k0 = (u & 7) * 8;
            long g = (((long)bh << 6) + d) * 1024 + t * 64 + k0;
            *(uint4*)(Vs + d * 72 + k0) = *(const uint4*)(VT + g);
        }
    };
    auto computeS = [&](f32x4* s) {
        #pragma unroll
        for (int kk = 0; kk < 2; kk++)
            #pragma unroll
            for (int j4 = 0; j4 < 4; j4++) {
                bf16x8 kh8 = *(const bf16x8*)(&Khs[(j4 * 16 + l15) * 72 + kk * 32 + q * 8]);
                bf16x8 kl8 = *(const bf16x8*)(&Kls[(j4 * 16 + l15) * 72 + kk * 32 + q * 8]);
                s[j4] = __builtin_amdgcn_mfma_f32_16x16x32_bf16(afh[kk], kh8, s[j4], 0, 0, 0);
                s[j4] = __builtin_amdgcn_mfma_f32_16x16x32_bf16(afh[kk], kl8, s[j4], 0, 0, 0);
                s[j4] = __builtin_amdgcn_mfma_f32_16x16x32_bf16(afl[kk], kh8, s[j4], 0, 0, 0);
            }
    };
    auto pv = [&]() {
        #pragma unroll
        for (int kk = 0; kk < 2; kk++) {
            bf16x8 ap = *(const bf16x8*)(&Ps[w][l15 * 72 + kk * 32 + q * 8]);
            #pragma unroll
            for (int j4 = 0; j4 < 4; j4++) {
                bf16x8 bv = *(const bf16x8*)(&Vs[(j4 * 16 + l15) * 72 + kk * 32 + q * 8]);
                o[j4] = __builtin_amdgcn_mfma_f32_16x16x32_bf16(ap, bv, o[j4], 0, 0, 0);
            }
        }
    };

    if (SCORE) {
        // ---- pass 1: row max + denom ----
        for (int t = 0; t < 16; ++t) {
            __syncthreads();
            stageK(t);
            __syncthreads();
            f32x4 s[4] = {};
            computeS(s);
            #pragma unroll
            for (int r = 0; r < 4; r++) {
                float tm = fmaxf(fmaxf(s[0][r], s[1][r]), fmaxf(s[2][r], s[3][r]));
                #pragma unroll
                for (int off = 1; off < 16; off <<= 1) tm = fmaxf(tm, __shfl_xor(tm, off));
                float mn = fmaxf(mr[r], tm);
                float ss = __expf(s[0][r] - mn) + __expf(s[1][r] - mn)
                         + __expf(s[2][r] - mn) + __expf(s[3][r] - mn);
                #pragma unroll
                for (int off = 1; off < 16; off <<= 1) ss += __shfl_xor(ss, off);
                lr[r] = lr[r] * __expf(mr[r] - mn) + ss;
                mr[r] = mn;
            }
        }
        float linv[4];
        #pragma unroll
        for (int r = 0; r < 4; r++) linv[r] = 1.f / lr[r];
        // ---- pass 2: normalized P, colsums, PV ----
        for (int t = 0; t < 16; ++t) {
            __syncthreads();
            stageK(t); stageV(t);
            __syncthreads();
            f32x4 s[4] = {};
            computeS(s);
            float cs[4] = {0.f, 0.f, 0.f, 0.f};
            #pragma unroll
            for (int j4 = 0; j4 < 4; j4++)
                #pragma unroll
                for (int r = 0; r < 4; r++) {
                    float p = __expf(s[j4][r] - mr[r]) * linv[r];
                    cs[j4] += p;
                    Ps[w][(q * 4 + r) * 72 + j4 * 16 + l15] = f2bf(p);
                }
            #pragma unroll
            for (int j4 = 0; j4 < 4; j4++) {
                cs[j4] += __shfl_xor(cs[j4], 16);
                cs[j4] += __shfl_xor(cs[j4], 32);
            }
            if (q == 0) {
                long pb = (((long)(bh * 16 + rt) * 4 + w) << 10) + t * 64;
                #pragma unroll
                for (int j4 = 0; j4 < 4; j4++) PSCW[pb + j4 * 16 + l15] = cs[j4];
            }
            __syncthreads();
            pv();
        }
    } else {
        // ---- single-pass online-softmax flash ----
        for (int t = 0; t < 16; ++t) {
            __syncthreads();
            stageK(t); stageV(t);
            __syncthreads();
            f32x4 s[4] = {};
            computeS(s);
            float corr[4];
            #pragma unroll
            for (int r = 0; r < 4; r++) {
                float tm = fmaxf(fmaxf(s[0][r], s[1][r]), fmaxf(s[2][r], s[3][r]));
                #pragma unroll
                for (int off = 1; off < 16; off <<= 1) tm = fmaxf(tm, __shfl_xor(tm, off));
                float mn = fmaxf(mr[r], tm);
                corr[r] = __expf(mr[r] - mn);
                mr[r] = mn;
            }
            float ssr[4] = {0.f, 0.f, 0.f, 0.f};
            #pragma unroll
            for (int j4 = 0; j4 < 4; j4++)
                #pragma unroll
                for (int r = 0; r < 4; r++) {
                    float p = __expf(s[j4][r] - mr[r]);
                    ssr[r] += p;
                    Ps[w][(q * 4 + r) * 72 + j4 * 16 + l15] = f2bf(p);
                }
            #pragma unroll
            for (int r = 0; r < 4; r++) {
                float ss = ssr[r];
                #pragma unroll
                for (int off = 1; off < 16; off <<= 1) ss += __shfl_xor(ss, off);
                lr[r] = lr[r] * corr[r] + ss;
            }
            #pragma unroll
            for (int j4 = 0; j4 < 4; j4++)
                #pragma unroll
                for (int r = 0; r < 4; r++) o[j4][r] *= corr[r];
            __syncthreads();
            pv();
        }
    }

    float fin[4];
    #pragma unroll
    for (int r = 0; r < 4; r++) fin[r] = SCORE ? 1.f : (1.f / lr[r]);
    long obase = (((long)bh << 10) + rt * 64 + w * 16 + q * 4) * 64;
    #pragma unroll
    for (int j4 = 0; j4 < 4; j4++)
        #pragma unroll
        for (int r = 0; r < 4; r++)
            O[obase + (long)r * 64 + j4 * 16 + l15] = o[j4][r] * fin[r];
}

// topk with fused colsum-partial reduction (replaces score_reduce + old topk)
__global__ __launch_bounds__(256) void topk_kernel(const float* __restrict__ PSCW, int* __restrict__ topk) {
    __shared__ float s[1024];
    int z = blockIdx.x; int tid = threadIdx.x;
    for (int i = tid; i < 1024; i += 256) {
        float v = 0.f;
        for (int rw = 0; rw < 64; rw++) v += PSCW[(((long)z * 64 + rw) << 10) + i];
        s[i] = (v == v) ? v : -INFINITY;
    }
    __syncthreads();
    for (int i = tid; i < 1024; i += 256) {
        float si = s[i]; int r = 0;
        for (int j = 0; j < 1024; j++) {
            float sj = s[j];
            r += (sj > si) || (sj == si && j < i);
        }
        if (r < 256) topk[z * 256 + r] = i;
    }
}

__global__ __launch_bounds__(256) void gather_tokf_kernel(const float* __restrict__ coarse,
                                                          const int* __restrict__ topk,
                                                          float* __restrict__ tokf) {
    long idx = (long)blockIdx.x * 256 + threadIdx.x;
    int d = (int)(idx & 63); int t = (int)((idx >> 6) & 3);
    int j = (int)((idx >> 8) & 255); int bh = (int)(idx >> 16);
    int p = topk[bh * 256 + j] & 1023;
    int py = p >> 5, px = p & 31;
    int dy = t >> 1, dx = t & 1;
    int b = bh >> 2, h = bh & 3;
    tokf[idx] = coarse[(((long)b * 256 + h * 64 + d) * 64 + (2 * py + dy)) * 64 + (2 * px + dx)];
}

__global__ __launch_bounds__(256) void scatter_add_kernel(float* __restrict__ coarse,
                                                          const int* __restrict__ topk,
                                                          const float* __restrict__ outf) {
    long idx = (long)blockIdx.x * 256 + threadIdx.x;
    int d = (int)(idx & 63); int t = (int)((idx >> 6) & 3);
    int j = (int)((idx >> 8) & 255); int bh = (int)(idx >> 16);
    int p = topk[bh * 256 + j] & 1023;
    int py = p >> 5, px = p & 31;
    int dy = t >> 1, dx = t & 1;
    int b = bh >> 2, h = bh & 3;
    coarse[(((long)b * 256 + h * 64 + d) * 64 + (2 * py + dy)) * 64 + (2 * px + dx)] += outf[idx];
}

__global__ __launch_bounds__(64) void dw_bn_relu6_kernel(const float* __restrict__ y, const float* __restrict__ w9,
                                                         const float* __restrict__ s1, const float* __restrict__ t1,
                                                         float* __restrict__ out) {
    int gid = blockIdx.x;
    int row = gid & 63; int bc = gid >> 6; int c = bc & 255;
    int x = threadIdx.x;
    const float* base = y + (long)bc * 4096;
    float acc = 0.f;
    #pragma unroll
    for (int ky = 0; ky < 3; ky++) {
        int yy = row + ky - 1;
        if (yy < 0 || yy >= 64) continue;
        #pragma unroll
        for (int kx = 0; kx < 3; kx++) {
            int xx = x + kx - 1;
            if (xx < 0 || xx >= 64) continue;
            acc += base[yy * 64 + xx] * w9[c * 9 + ky * 3 + kx];
        }
    }
    out[(long)gid * 64 + x] = relu6(acc * s1[c] + t1[c]);
}

// ---------------- launch ----------------
extern "C" void kernel_launch(void* const* d_in, const int* in_sizes, int n_in,
                              void* d_out, int out_size, void* d_ws, size_t ws_size,
                              hipStream_t stream) {
    if (ws_size < (size_t)WS_FLOATS * 4) return;

    const void* x      = d_in[0];
    const void* down_w = d_in[1];
    const void* down_b = d_in[2];
    const void* up_w   = d_in[3];
    const void* up_b   = d_in[4];
    const void* wqkv_c = d_in[5];
    const void* bqkv_c = d_in[6];
    const void* wqkv_f = d_in[7];
    const void* bqkv_f = d_in[8];
    const void* dw_w   = d_in[9];
    const void* bn1_g  = d_in[10];
    const void* bn1_b  = d_in[11];
    const void* bn1_m  = d_in[12];
    const void* bn1_v  = d_in[13];
    const void* pw_w   = d_in[14];
    const void* bn2_g  = d_in[15];
    const void* bn2_b  = d_in[16];
    const void* bn2_m  = d_in[17];
    const void* bn2_v  = d_in[18];

    float* ws = (float*)d_ws;
    int* flagp = (int*)(ws + OFF_FLAG);
    dim3 blk(256);

    hipMemsetAsync(flagp, 0, sizeof(int), stream);
    detect_kernel<<<1, blk, 0, stream>>>(x, flagp);

    // split x and down_w into bf16 hi/lo
    split_pack_kernel<<<32768, blk, 0, stream>>>(x, (unsigned int*)(ws + OFF_XHL), 8388608, flagp);
    split_kernel<<<4096, blk, 0, stream>>>(down_w, (unsigned short*)(ws + OFF_DOWNW),
                                           (unsigned short*)(ws + OFF_DOWNWL), 1048576, flagp);
    prep_misc_kernel<<<367, blk, 0, stream>>>(down_b, up_b, bqkv_c, bqkv_f, dw_w, wqkv_c, wqkv_f, pw_w,
                                              bn1_g, bn1_b, bn1_m, bn1_v, bn2_g, bn2_b, bn2_m, bn2_v,
                                              ws, flagp);
    prep_up_kernel<<<4096, blk, 0, stream>>>(up_w, (unsigned short*)(ws + OFF_UPW4), flagp);

    // down conv (bf16x2 MFMA, topk-safe): M=8192, N=256, K=4096 -> xd NHWC
    gemm_mfma_x2<<<dim3(4, 128, 1), blk, 0, stream>>>((const unsigned int*)(ws + OFF_XHL),
        (const unsigned short*)(ws + OFF_DOWNW), (const unsigned short*)(ws + OFF_DOWNWL),
        ws + OFF_XDHWC, ws + OFF_DOWNB);

    // coarse qkv: M=32768, N=192, K=64 -> split bf16 planes (Q scaled)
    gemm_k<2><<<dim3(3, 512, 1), blk, 0, stream>>>(ws + OFF_XDHWC, ws + OFF_WQKVC,
        (unsigned short*)(ws + OFF_QH), 64, 64, 64, ws + OFF_BQKVC);

    // coarse MFMA attention (two-pass, + per-wave colsum partials) -> OUTC, PSCW
    attn_mfma<true><<<dim3(16, 32), blk, 0, stream>>>((const unsigned short*)(ws + OFF_QH),
        ws + OFF_OUTC, ws + OFF_PSCW);
    topk_kernel<<<32, blk, 0, stream>>>(ws + OFF_PSCW, (int*)(ws + OFF_TOPK));

    // up conv (bf16 MFMA, post-topk): M=8192, N=256, K=1024, z=cls -> coarse NCHW (overwrites XHL/PSCW)
    gemm_mfma<4, 2><<<dim3(4, 128, 4), blk, 0, stream>>>(ws + OFF_OUTC, (unsigned short*)(ws + OFF_UPW4),
        ws + OFF_COARSE, 1024, 0, 262144, 0, 1024, ws + OFF_UPB, nullptr, nullptr, flagp);

    // fine attention
    gather_tokf_kernel<<<8192, blk, 0, stream>>>(ws + OFF_COARSE, (const int*)(ws + OFF_TOPK), ws + OFF_XDHWC);
    gemm_k<3><<<dim3(3, 512, 1), blk, 0, stream>>>(ws + OFF_XDHWC, ws + OFF_WQKVF,
        (unsigned short*)(ws + OFF_QH), 64, 64, 64, ws + OFF_BQKVF);
    attn_mfma<false><<<dim3(16, 32), blk, 0, stream>>>((const unsigned short*)(ws + OFF_QH),
        ws + OFF_OUTC, nullptr);
    scatter_add_kernel<<<8192, blk, 0, stream>>>(ws + OFF_COARSE, (const int*)(ws + OFF_TOPK), ws + OFF_OUTC);

    // depthwise + bn1 + relu6 -> T1
    dw_bn_relu6_kernel<<<131072, dim3(64), 0, stream>>>(ws + OFF_COARSE, ws + OFF_DWW,
        ws + OFF_BN1S, ws + OFF_BN1T, ws + OFF_T1);

    // pointwise + bn2 + relu6 (bf16 MFMA) -> d_out: M=4096, N=256, K=256, z=batch
    gemm_mfma<5, 0><<<dim3(4, 64, 8), blk, 0, stream>>>(ws + OFF_T1, (unsigned short*)(ws + OFF_PWW),
        nullptr, 256, 1048576, 0, 4096, 256, ws + OFF_BN2S, ws + OFF_BN2T, d_out, flagp);
}

// Round 11
// 759.697 us; speedup vs baseline: 1.1140x; 1.0199x over previous
//
#include <hip/hip_runtime.h>
#include <hip/hip_bf16.h>

typedef __hip_bfloat16 bf16;
typedef __bf16 bf16x8 __attribute__((ext_vector_type(8)));
typedef float f32x4 __attribute__((ext_vector_type(4)));

// B=8, C=256, H=W=64, nh=4, HD=64, coarse tokens N=1024 (32x32), kf=256, fine tokens 1024.
// fp32 in/out (auto-detected). Top-k-critical paths (down-conv, attention QK^T) use bf16x2
// split-precision MFMA (error ~2^-17, fp32-class => tie-safe); PV + post-topk GEMMs plain bf16 MFMA.

// ---------------- workspace layout (float offsets) ----------------
#define OFF_XDHWC    0L
#define OFF_QH       2097152L     // 5 planes (ushort units vs this base):
                                  //   QH +0, QL +2097152, KH +4194304, KL +6291456, VT +8388608
#define OFF_T1       0L           // overlay on trunk
#define OFF_OUTC     8388608L
#define OFF_COARSE   10485760L    // XHL (packed hi|lo x) first, then PSCW, then coarse NCHW -> y
#define OFF_XHL      10485760L    // 8,388,608 uint (hi|lo packed bf16 of x, NCHW)
#define OFF_PSCW     10485760L    // 2M floats: per-(bh,rt,wave) colsum partials (XHL dead by then)
#define OFF_SCORE    19398656L
#define OFF_TOPK     19431424L
#define OFF_DOWNW    19439616L    // WH bf16 [co][k] (1M ushort); WL at +524288 floats
#define OFF_DOWNWL   19963904L
#define OFF_UPW4     20488192L    // bf16 (ushort) [cls][co][k]
#define OFF_WQKVC    21536768L
#define OFF_BQKVC    21549056L
#define OFF_WQKVF    21549248L
#define OFF_BQKVF    21561536L
#define OFF_PWW      21561728L    // bf16 (ushort) [co][ci]
#define OFF_DWW      21627264L
#define OFF_BN1S     21629568L
#define OFF_BN1T     21629824L
#define OFF_BN2S     21630080L
#define OFF_BN2T     21630336L
#define OFF_DOWNB    21630592L
#define OFF_UPB      21630848L
#define OFF_FLAG     21631104L    // 1 int: 1 = bf16 world, 0 = fp32 world (default via memset)
#define WS_FLOATS    21631360L

__device__ __forceinline__ float relu6(float v) { return v < 0.f ? 0.f : (v > 6.f ? 6.f : v); }

__device__ __forceinline__ float ldin(const void* p, long i, int flag) {
    return flag ? __bfloat162float(((const bf16*)p)[i]) : ((const float*)p)[i];
}

// fp32 -> bf16 bits, round-to-nearest-even
__device__ __forceinline__ unsigned short f2bf(float f) {
    unsigned int b = __float_as_uint(f);
    b += 0x7FFFu + ((b >> 16) & 1u);
    return (unsigned short)(b >> 16);
}

// ---------------- dtype detector ----------------
__global__ __launch_bounds__(256) void detect_kernel(const void* __restrict__ x, int* __restrict__ flag) {
    __shared__ int cnt[256];
    int tid = threadIdx.x;
    int c = 0;
    for (int i = tid; i < 4096; i += 256) {
        long idx = (long)i * 2047;
        float v = __bfloat162float(((const bf16*)x)[idx]);
        float a = fabsf(v);
        if (isfinite(v) && a > 1e-8f && a < 100.f) c++;
    }
    cnt[tid] = c; __syncthreads();
    for (int s = 128; s > 0; s >>= 1) { if (tid < s) cnt[tid] += cnt[tid + s]; __syncthreads(); }
    if (tid == 0 && cnt[0] >= 3686) *flag = 1;
}

// ---------------- prep kernels (dual-dtype) ----------------
// split to packed hi|lo uint (x): low16 = bf16(v), high16 = bf16(v - hi)
__global__ __launch_bounds__(256) void split_pack_kernel(const void* __restrict__ in, unsigned int* __restrict__ out,
                                                         int n, const int* __restrict__ flagp) {
    int flag = *flagp;
    int i = blockIdx.x * 256 + threadIdx.x;
    if (i < n) {
        float v = ldin(in, i, flag);
        unsigned short h = f2bf(v);
        float fh = __uint_as_float(((unsigned int)h) << 16);
        unsigned short l = f2bf(v - fh);
        out[i] = (unsigned int)h | ((unsigned int)l << 16);
    }
}

// split to separate hi/lo planes (down_w, layout [co][k] is identity with input flat layout)
__global__ __launch_bounds__(256) void split_kernel(const void* __restrict__ in,
                                                    unsigned short* __restrict__ hi, unsigned short* __restrict__ lo,
                                                    int n, const int* __restrict__ flagp) {
    int flag = *flagp;
    int i = blockIdx.x * 256 + threadIdx.x;
    if (i < n) {
        float v = ldin(in, i, flag);
        unsigned short h = f2bf(v);
        float fh = __uint_as_float(((unsigned int)h) << 16);
        hi[i] = h;
        lo[i] = f2bf(v - fh);
    }
}

// up_w [ci,co,4,4] -> W4 bf16 [cls][co][ci*4+j]
__global__ __launch_bounds__(256) void prep_up_kernel(const void* __restrict__ w, unsigned short* __restrict__ W4,
                                                      const int* __restrict__ flagp) {
    int flag = *flagp;
    int idx = blockIdx.x * 256 + threadIdx.x;
    int cls = idx >> 18; int rem = idx & 262143;
    int co = rem >> 10; int q = rem & 1023;
    int ci = q >> 2; int j = q & 3;
    int pa = cls >> 1, pb = cls & 1;
    int jy = j >> 1, jx = j & 1;
    int ky = (pa == 0) ? (jy ? 3 : 1) : (jy ? 0 : 2);
    int kx = (pb == 0) ? (jx ? 3 : 1) : (jx ? 0 : 2);
    W4[idx] = f2bf(ldin(w, (((long)ci * 256 + co) * 4 + ky) * 4 + kx, flag));
}

// fused small-tensor prep: tqkv_c, tqkv_f, dw_w, biases, bn1/bn2, pw_w (replaces 10 launches)
__global__ __launch_bounds__(256) void prep_misc_kernel(
    const void* __restrict__ down_b, const void* __restrict__ up_b,
    const void* __restrict__ bqkv_c, const void* __restrict__ bqkv_f,
    const void* __restrict__ dw_w, const void* __restrict__ wqkv_c,
    const void* __restrict__ wqkv_f, const void* __restrict__ pw_w,
    const void* __restrict__ bn1_g, const void* __restrict__ bn1_b,
    const void* __restrict__ bn1_m, const void* __restrict__ bn1_v,
    const void* __restrict__ bn2_g, const void* __restrict__ bn2_b,
    const void* __restrict__ bn2_m, const void* __restrict__ bn2_v,
    float* __restrict__ ws, const int* __restrict__ flagp)
{
    int flag = *flagp;
    int bid = blockIdx.x, tid = threadIdx.x;
    if (bid < 48) {                        // wqkv_c transpose -> [j][d]
        int idx = bid * 256 + tid;
        int j = idx >> 6, d = idx & 63;
        ws[OFF_WQKVC + idx] = ldin(wqkv_c, d * 192 + j, flag);
    } else if (bid < 96) {                 // wqkv_f transpose
        int idx = (bid - 48) * 256 + tid;
        int j = idx >> 6, d = idx & 63;
        ws[OFF_WQKVF + idx] = ldin(wqkv_f, d * 192 + j, flag);
    } else if (bid < 105) {                // dw_w cvt (2304)
        int i = (bid - 96) * 256 + tid;
        if (i < 2304) ws[OFF_DWW + i] = ldin(dw_w, i, flag);
    } else if (bid == 105) {
        ws[OFF_DOWNB + tid] = ldin(down_b, tid, flag);
    } else if (bid == 106) {
        ws[OFF_UPB + tid] = ldin(up_b, tid, flag);
    } else if (bid == 107) {
        if (tid < 192) ws[OFF_BQKVC + tid] = ldin(bqkv_c, tid, flag);
    } else if (bid == 108) {
        if (tid < 192) ws[OFF_BQKVF + tid] = ldin(bqkv_f, tid, flag);
    } else if (bid == 109) {               // bn1 prep
        float gv = ldin(bn1_g, tid, flag), bv = ldin(bn1_b, tid, flag);
        float mv = ldin(bn1_m, tid, flag), vv = ldin(bn1_v, tid, flag);
        float inv = gv / sqrtf(vv + 1e-5f);
        ws[OFF_BN1S + tid] = inv; ws[OFF_BN1T + tid] = bv - mv * inv;
    } else if (bid == 110) {               // bn2 prep
        float gv = ldin(bn2_g, tid, flag), bv = ldin(bn2_b, tid, flag);
        float mv = ldin(bn2_m, tid, flag), vv = ldin(bn2_v, tid, flag);
        float inv = gv / sqrtf(vv + 1e-5f);
        ws[OFF_BN2S + tid] = inv; ws[OFF_BN2T + tid] = bv - mv * inv;
    } else {                               // pw_w -> bf16 (65536), blocks 111..366
        int i = (bid - 111) * 256 + tid;
        ((unsigned short*)(ws + OFF_PWW))[i] = f2bf(ldin(pw_w, i, flag));
    }
}

// ---------------- bf16x2 split-precision MFMA down-conv (top-k-safe) ----------------
// R1-exact structure (best measured: 122.9us): 64x64 tile, BK=32, grid 4x128.
// C[m,n] = conv; m=(b,oy,ox) M=8192, n=co N=256, k=(ci,ky,kx) K=4096.
// A from XHL (packed hi|lo NCHW), B from WH/WL. 3-term MFMA: hihi + hilo + lohi.
__global__ __launch_bounds__(256) void gemm_mfma_x2(
    const unsigned int* __restrict__ XHL,
    const unsigned short* __restrict__ WH, const unsigned short* __restrict__ WL,
    float* __restrict__ C, const float* __restrict__ e0)
{
    __shared__ __align__(16) unsigned short Ah[64 * 40];
    __shared__ __align__(16) unsigned short Al[64 * 40];
    __shared__ __align__(16) unsigned short Bh[64 * 40];
    __shared__ __align__(16) unsigned short Bl[64 * 40];
    int m0 = blockIdx.y * 64, n0 = blockIdx.x * 64;
    int tid = threadIdx.x;
    int w = tid >> 6, l = tid & 63, l15 = l & 15, q = l >> 4;
    unsigned int aR[8];
    uint4 bhR, blR;
    int bn = tid >> 2, bk = (tid & 3) * 8;

    auto loadA = [&](int k0) {
        #pragma unroll
        for (int i = 0; i < 8; i++) {
            int idx = i * 256 + tid;
            int kl = idx & 31, ml = idx >> 5;
            int m = m0 + ml, k = k0 + kl;
            int b = m >> 10, oy = (m >> 5) & 31, ox = m & 31;
            int c = k >> 4, ky = (k >> 2) & 3, kx = k & 3;
            int iy = 2 * oy - 1 + ky, ix = 2 * ox - 1 + kx;
            unsigned int v = 0;
            if ((unsigned)iy < 64u && (unsigned)ix < 64u)
                v = XHL[(((long)b * 256 + c) * 64 + iy) * 64 + ix];
            aR[i] = v;
        }
    };
    auto storeA = [&]() {
        #pragma unroll
        for (int i = 0; i < 8; i++) {
            int idx = i * 256 + tid;
            int kl = idx & 31, ml = idx >> 5;
            Ah[ml * 40 + kl] = (unsigned short)(aR[i] & 0xffffu);
            Al[ml * 40 + kl] = (unsigned short)(aR[i] >> 16);
        }
    };
    auto loadB = [&](int k0) {
        bhR = *(const uint4*)(WH + (long)(n0 + bn) * 4096 + (k0 + bk));
        blR = *(const uint4*)(WL + (long)(n0 + bn) * 4096 + (k0 + bk));
    };

    f32x4 acc[4] = {};
    loadA(0); loadB(0);
    for (int k0 = 0; k0 < 4096; k0 += 32) {
        storeA();
        *(uint4*)(&Bh[bn * 40 + bk]) = bhR;
        *(uint4*)(&Bl[bn * 40 + bk]) = blR;
        __syncthreads();
        if (k0 + 32 < 4096) { loadA(k0 + 32); loadB(k0 + 32); }
        bf16x8 afh = *(const bf16x8*)(&Ah[(w * 16 + l15) * 40 + q * 8]);
        bf16x8 afl = *(const bf16x8*)(&Al[(w * 16 + l15) * 40 + q * 8]);
        #pragma unroll
        for (int j4 = 0; j4 < 4; j4++) {
            bf16x8 bfh = *(const bf16x8*)(&Bh[(j4 * 16 + l15) * 40 + q * 8]);
            bf16x8 bfl = *(const bf16x8*)(&Bl[(j4 * 16 + l15) * 40 + q * 8]);
            acc[j4] = __builtin_amdgcn_mfma_f32_16x16x32_bf16(afh, bfh, acc[j4], 0, 0, 0);
            acc[j4] = __builtin_amdgcn_mfma_f32_16x16x32_bf16(afh, bfl, acc[j4], 0, 0, 0);
            acc[j4] = __builtin_amdgcn_mfma_f32_16x16x32_bf16(afl, bfh, acc[j4], 0, 0, 0);
        }
        __syncthreads();
    }
    #pragma unroll
    for (int j4 = 0; j4 < 4; j4++) {
        int n = n0 + j4 * 16 + l15;
        #pragma unroll
        for (int r = 0; r < 4; r++) {
            int m = m0 + w * 16 + q * 4 + r;
            C[(long)m * 256 + n] = acc[j4][r] + e0[n];
        }
    }
}

// ---------------- fp32 GEMM (coarse/fine qkv) -> split bf16 planes for MFMA attention ----------
// C[m,n] = sum_k A[m,k]*B[n,k] + e0[n].  n<64 -> Q (x0.125, split hi/lo), n<128 -> K (split),
// else V -> transposed plain bf16 [bh][d][tok].
template<int EPI>
__global__ __launch_bounds__(256) void gemm_k(
    const float* __restrict__ A, const float* __restrict__ B,
    unsigned short* __restrict__ out, int K, int sAm, int sBn, const float* __restrict__ e0)
{
    __shared__ float As[16][68];
    __shared__ float Bs[16][68];
    int m0 = blockIdx.y * 64;
    int n0 = blockIdx.x * 64;
    int tid = threadIdx.x;
    int tx = tid & 15, ty = tid >> 4;
    int l4 = tid >> 2, kq = (tid & 3) * 4;
    float4 aR, bR;

    auto loadA = [&](int k0) { aR = *(const float4*)(A + (long)(m0 + l4) * sAm + (k0 + kq)); };
    auto loadB = [&](int k0) { bR = *(const float4*)(B + (long)(n0 + l4) * sBn + (k0 + kq)); };

    float acc[4][4] = {};
    loadA(0); loadB(0);
    for (int k0 = 0; k0 < K; k0 += 16) {
        As[kq + 0][l4] = aR.x; As[kq + 1][l4] = aR.y; As[kq + 2][l4] = aR.z; As[kq + 3][l4] = aR.w;
        Bs[kq + 0][l4] = bR.x; Bs[kq + 1][l4] = bR.y; Bs[kq + 2][l4] = bR.z; Bs[kq + 3][l4] = bR.w;
        __syncthreads();
        if (k0 + 16 < K) { loadA(k0 + 16); loadB(k0 + 16); }
        #pragma unroll
        for (int kk = 0; kk < 16; ++kk) {
            float4 av = *reinterpret_cast<const float4*>(&As[kk][ty * 4]);
            float4 bv = *reinterpret_cast<const float4*>(&Bs[kk][tx * 4]);
            float a[4] = {av.x, av.y, av.z, av.w};
            float b[4] = {bv.x, bv.y, bv.z, bv.w};
            #pragma unroll
            for (int i = 0; i < 4; i++)
                #pragma unroll
                for (int j = 0; j < 4; j++)
                    acc[i][j] += a[i] * b[j];
        }
        __syncthreads();
    }
    #pragma unroll
    for (int i = 0; i < 4; i++) {
        int m = m0 + ty * 4 + i;
        int bh, tok;
        if (EPI == 2) { int bi = m >> 12; int h = m & 3; tok = (m >> 2) & 1023; bh = bi * 4 + h; }
        else          { bh = m >> 10; tok = m & 1023; }
        #pragma unroll
        for (int j = 0; j < 4; j++) {
            int n = n0 + tx * 4 + j;
            float v = acc[i][j] + e0[n];
            if (n < 64) {
                v *= 0.125f;  // fold attention scale into Q
                unsigned short hb = f2bf(v);
                float fh = __uint_as_float(((unsigned int)hb) << 16);
                unsigned short lb = f2bf(v - fh);
                long p = (((long)bh << 10) + tok) * 64 + n;
                out[p] = hb; out[p + 2097152] = lb;
            } else if (n < 128) {
                unsigned short hb = f2bf(v);
                float fh = __uint_as_float(((unsigned int)hb) << 16);
                unsigned short lb = f2bf(v - fh);
                long p = (((long)bh << 10) + tok) * 64 + (n - 64);
                out[p + 4194304] = hb; out[p + 6291456] = lb;
            } else {
                out[8388608 + (((long)bh << 6) + (n - 128)) * 1024 + tok] = f2bf(v);
            }
        }
    }
}

// ---------------- bf16 MFMA GEMM (post-topk) ----------------
// AMODE==2 (up-conv): per-slot gather geometry is K-invariant -> hoist spatial base + validity;
// per-iter index math reduced to ci = ci0 + (k0>>2) and two shifts.
template<int EPI, int AMODE>
__global__ __launch_bounds__(256) void gemm_mfma(
    const float* __restrict__ A, const unsigned short* __restrict__ Bb, float* __restrict__ C,
    int K, long sAz, long sBz, int sAk, int sBn,
    const float* __restrict__ e0, const float* __restrict__ e1,
    void* __restrict__ ob, const int* __restrict__ flagp)
{
    __shared__ __align__(16) unsigned short Asb[64 * 40];
    __shared__ __align__(16) unsigned short Bsb[64 * 40];
    int z = blockIdx.z;
    if (AMODE == 0) A += (long)z * sAz;
    Bb += (long)z * sBz;
    int m0 = blockIdx.y * 64, n0 = blockIdx.x * 64;
    int tid = threadIdx.x;
    int w = tid >> 6, l = tid & 63;
    int l15 = l & 15, q = l >> 4;
    float aR[8];
    uint4 bR;

    int sbA[8], ci0A[8];
    if (AMODE != 0) {
        #pragma unroll
        for (int i = 0; i < 8; i++) {
            int idx = i * 256 + tid;
            int kl = idx & 31, ml = idx >> 5;
            int m = m0 + ml;
            int b = m >> 10, y = (m >> 5) & 31, x2 = m & 31;
            int j = kl & 3;
            int pa = z >> 1, pb = z & 1;
            int jy = j >> 1, jx = j & 1;
            int dy = (pa == 0) ? (jy ? -1 : 0) : (jy ? 1 : 0);
            int dx = (pb == 0) ? (jx ? -1 : 0) : (jx ? 1 : 0);
            int yy = y + dy, xx = x2 + dx;
            ci0A[i] = kl >> 2;
            sbA[i] = ((unsigned)yy < 32u && (unsigned)xx < 32u)
                     ? (b * 262144 + (yy * 32 + xx) * 64) : -1;
        }
    }

    auto loadA = [&](int k0) {
        if (AMODE == 0) {
            #pragma unroll
            for (int i = 0; i < 8; i++) {
                int idx = i * 256 + tid;
                int ml = idx & 63, kl = idx >> 6;
                aR[i] = A[(long)(k0 + kl) * sAk + (m0 + ml)];
            }
        } else {
            int cq = k0 >> 2;
            #pragma unroll
            for (int i = 0; i < 8; i++) {
                int ci = ci0A[i] + cq;
                aR[i] = (sbA[i] >= 0) ? A[sbA[i] + ((ci >> 6) << 16) + (ci & 63)] : 0.f;
            }
        }
    };
    auto storeA = [&]() {
        #pragma unroll
        for (int i = 0; i < 8; i++) {
            int idx = i * 256 + tid;
            int ml, kl;
            if (AMODE == 0) { ml = idx & 63; kl = idx >> 6; }
            else            { kl = idx & 31; ml = idx >> 5; }
            Asb[ml * 40 + kl] = f2bf(aR[i]);
        }
    };
    int bn = tid >> 2, bk = (tid & 3) * 8;
    auto loadB = [&](int k0) {
        bR = *(const uint4*)(Bb + (long)(n0 + bn) * sBn + (k0 + bk));
    };

    f32x4 acc[4] = {};
    loadA(0); loadB(0);
    for (int k0 = 0; k0 < K; k0 += 32) {
        storeA();
        *(uint4*)(&Bsb[bn * 40 + bk]) = bR;
        __syncthreads();
        if (k0 + 32 < K) { loadA(k0 + 32); loadB(k0 + 32); }
        bf16x8 af = *(const bf16x8*)(&Asb[(w * 16 + l15) * 40 + q * 8]);
        #pragma unroll
        for (int j4 = 0; j4 < 4; j4++) {
            bf16x8 bf = *(const bf16x8*)(&Bsb[(j4 * 16 + l15) * 40 + q * 8]);
            acc[j4] = __builtin_amdgcn_mfma_f32_16x16x32_bf16(af, bf, acc[j4], 0, 0, 0);
        }
        __syncthreads();
    }
    int oflag = (EPI == 5) ? *flagp : 0;
    #pragma unroll
    for (int j4 = 0; j4 < 4; j4++) {
        int n = n0 + j4 * 16 + l15;
        #pragma unroll
        for (int r = 0; r < 4; r++) {
            int m = m0 + w * 16 + q * 4 + r;
            float v = acc[j4][r];
            if (EPI == 4) {
                v += e0[n];
                int pa = z >> 1, pb = z & 1;
                int bi = m >> 10, y = (m >> 5) & 31, x2 = m & 31;
                C[(((long)bi * 256 + n) * 64 + (2 * y + pa)) * 64 + (2 * x2 + pb)] = v;
            } else {
                v = relu6(v * e0[n] + e1[n]);
                long oidx = (long)z * 1048576 + (long)n * 4096 + m;
                if (oflag) ((bf16*)ob)[oidx] = __float2bfloat16(v);
                else       ((float*)ob)[oidx] = v;
            }
        }
    }
}

// ---------------- MFMA attention: [bh=32][N=1024][D=64], scale folded into Q ----------------
// Planes (ushort offsets from P0): QH +0, QL +2097152, KH +4194304, KL +6291456, VT +8388608.
// QK^T: split-precision 3-term bf16x2 (fp32-class logits => topk-safe scores).
// PV:   plain bf16 (P normalized/bounded by 1; same error class as post-topk bf16 GEMMs).
// R11: stage 2 K-tiles (128 tokens) per barrier pair -> barriers 48->16 (SCORE) / 32->16
// (flash) per dispatch, load-latency exposures halved. Staging stays transient global->LDS
// (no persistent prefetch regs -- the R8/R9 spill lesson). LDS 63 KB, 2 blocks/CU unchanged.
template<bool SCORE>
__global__ __launch_bounds__(256) void attn_mfma(
    const unsigned short* __restrict__ P0,
    float* __restrict__ O, float* __restrict__ PSCW)
{
    const unsigned short* QH = P0;
    const unsigned short* QL = P0 + 2097152;
    const unsigned short* KH = P0 + 4194304;
    const unsigned short* KL = P0 + 6291456;
    const unsigned short* VT = P0 + 8388608;
    __shared__ __align__(16) unsigned short Khs[2][64 * 72];
    __shared__ __align__(16) unsigned short Kls[2][64 * 72];
    __shared__ __align__(16) unsigned short Vs[2][64 * 72];
    __shared__ __align__(16) unsigned short Ps[4][16 * 72];   // per-wave private P tile
    int bh = blockIdx.y, rt = blockIdx.x;
    int tid = threadIdx.x;
    int w = tid >> 6, l = tid & 63, l15 = l & 15, q = l >> 4;

    // Q fragments: rows rt*64 + w*16 + l15, dims kk*32 + q*8 (+0..7). Loaded once.
    long qoff = (((long)bh << 10) + rt * 64 + w * 16 + l15) * 64 + q * 8;
    bf16x8 afh[2], afl[2];
    afh[0] = *(const bf16x8*)(QH + qoff);
    afh[1] = *(const bf16x8*)(QH + qoff + 32);
    afl[0] = *(const bf16x8*)(QL + qoff);
    afl[1] = *(const bf16x8*)(QL + qoff + 32);

    float mr[4], lr[4];
    #pragma unroll
    for (int r = 0; r < 4; r++) { mr[r] = -1e30f; lr[r] = 0.f; }
    f32x4 o[4] = {};

    // stage 128 tokens (2 tiles) of K hi/lo
    auto stageK2 = [&](int tt) {
        #pragma unroll
        for (int i = 0; i < 4; i++) {
            int u = tid + i * 256;
            int tok = u >> 3, dp = (u & 7) * 8;   // tok 0..127
            int th = tok >> 6, tl = tok & 63;
            long g = (((long)bh << 10) + tt * 128 + tok) * 64 + dp;
            *(uint4*)(&Khs[th][tl * 72 + dp]) = *(const uint4*)(KH + g);
            *(uint4*)(&Kls[th][tl * 72 + dp]) = *(const uint4*)(KL + g);
        }
    };
    // stage 128 tokens (2 tiles) of V^T
    auto stageV2 = [&](int tt) {
        #pragma unroll
        for (int i = 0; i < 4; i++) {
            int u = tid + i * 256;
            int d = u >> 4, k0 = (u & 15) * 8;    // d 0..63, k0 0..120
            int th = k0 >> 6, kl = k0 & 63;
            long g = (((long)bh << 6) + d) * 1024 + tt * 128 + k0;
            *(uint4*)(&Vs[th][d * 72 + kl]) = *(const uint4*)(VT + g);
        }
    };
    auto computeS = [&](f32x4* s, int h) {
        #pragma unroll
        for (int kk = 0; kk < 2; kk++)
            #pragma unroll
            for (int j4 = 0; j4 < 4; j4++) {
                bf16x8 kh8 = *(const bf16x8*)(&Khs[h][(j4 * 16 + l15) * 72 + kk * 32 + q * 8]);
                bf16x8 kl8 = *(const bf16x8*)(&Kls[h][(j4 * 16 + l15) * 72 + kk * 32 + q * 8]);
                s[j4] = __builtin_amdgcn_mfma_f32_16x16x32_bf16(afh[kk], kh8, s[j4], 0, 0, 0);
                s[j4] = __builtin_amdgcn_mfma_f32_16x16x32_bf16(afh[kk], kl8, s[j4], 0, 0, 0);
                s[j4] = __builtin_amdgcn_mfma_f32_16x16x32_bf16(afl[kk], kh8, s[j4], 0, 0, 0);
            }
    };
    auto pv = [&](int h) {
        #pragma unroll
        for (int kk = 0; kk < 2; kk++) {
            bf16x8 ap = *(const bf16x8*)(&Ps[w][l15 * 72 + kk * 32 + q * 8]);
            #pragma unroll
            for (int j4 = 0; j4 < 4; j4++) {
                bf16x8 bv = *(const bf16x8*)(&Vs[h][(j4 * 16 + l15) * 72 + kk * 32 + q * 8]);
                o[j4] = __builtin_amdgcn_mfma_f32_16x16x32_bf16(ap, bv, o[j4], 0, 0, 0);
            }
        }
    };

    if (SCORE) {
        // ---- pass 1: row max + denom ----
        for (int tt = 0; tt < 8; ++tt) {
            __syncthreads();
            stageK2(tt);
            __syncthreads();
            #pragma unroll
            for (int h = 0; h < 2; ++h) {
                f32x4 s[4] = {};
                computeS(s, h);
                #pragma unroll
                for (int r = 0; r < 4; r++) {
                    float tm = fmaxf(fmaxf(s[0][r], s[1][r]), fmaxf(s[2][r], s[3][r]));
                    #pragma unroll
                    for (int off = 1; off < 16; off <<= 1) tm = fmaxf(tm, __shfl_xor(tm, off));
                    float mn = fmaxf(mr[r], tm);
                    float ss = __expf(s[0][r] - mn) + __expf(s[1][r] - mn)
                             + __expf(s[2][r] - mn) + __expf(s[3][r] - mn);
                    #pragma unroll
                    for (int off = 1; off < 16; off <<= 1) ss += __shfl_xor(ss, off);
                    lr[r] = lr[r] * __expf(mr[r] - mn) + ss;
                    mr[r] = mn;
                }
            }
        }
        float linv[4];
        #pragma unroll
        for (int r = 0; r < 4; r++) linv[r] = 1.f / lr[r];
        // ---- pass 2: normalized P, colsums, PV ----
        for (int tt = 0; tt < 8; ++tt) {
            __syncthreads();
            stageK2(tt); stageV2(tt);
            __syncthreads();
            #pragma unroll
            for (int h = 0; h < 2; ++h) {
                int t = tt * 2 + h;
                f32x4 s[4] = {};
                computeS(s, h);
                float cs[4] = {0.f, 0.f, 0.f, 0.f};
                #pragma unroll
                for (int j4 = 0; j4 < 4; j4++)
                    #pragma unroll
                    for (int r = 0; r < 4; r++) {
                        float p = __expf(s[j4][r] - mr[r]) * linv[r];
                        cs[j4] += p;
                        Ps[w][(q * 4 + r) * 72 + j4 * 16 + l15] = f2bf(p);
                    }
                #pragma unroll
                for (int j4 = 0; j4 < 4; j4++) {
                    cs[j4] += __shfl_xor(cs[j4], 16);
                    cs[j4] += __shfl_xor(cs[j4], 32);
                }
                if (q == 0) {
                    long pb = (((long)(bh * 16 + rt) * 4 + w) << 10) + t * 64;
                    #pragma unroll
                    for (int j4 = 0; j4 < 4; j4++) PSCW[pb + j4 * 16 + l15] = cs[j4];
                }
                pv(h);
            }
        }
    } else {
        // ---- single-pass online-softmax flash ----
        for (int tt = 0; tt < 8; ++tt) {
            __syncthreads();
            stageK2(tt); stageV2(tt);
            __syncthreads();
            #pragma unroll
            for (int h = 0; h < 2; ++h) {
                f32x4 s[4] = {};
                computeS(s, h);
                float corr[4];
                #pragma unroll
                for (int r = 0; r < 4; r++) {
                    float tm = fmaxf(fmaxf(s[0][r], s[1][r]), fmaxf(s[2][r], s[3][r]));
                    #pragma unroll
                    for (int off = 1; off < 16; off <<= 1) tm = fmaxf(tm, __shfl_xor(tm, off));
                    float mn = fmaxf(mr[r], tm);
                    corr[r] = __expf(mr[r] - mn);
                    mr[r] = mn;
                }
                float ssr[4] = {0.f, 0.f, 0.f, 0.f};
                #pragma unroll
                for (int j4 = 0; j4 < 4; j4++)
                    #pragma unroll
                    for (int r = 0; r < 4; r++) {
                        float p = __expf(s[j4][r] - mr[r]);
                        ssr[r] += p;
                        Ps[w][(q * 4 + r) * 72 + j4 * 16 + l15] = f2bf(p);
                    }
                #pragma unroll
                for (int r = 0; r < 4; r++) {
                    float ss = ssr[r];
                    #pragma unroll
                    for (int off = 1; off < 16; off <<= 1) ss += __shfl_xor(ss, off);
                    lr[r] = lr[r] * corr[r] + ss;
                }
                #pragma unroll
                for (int j4 = 0; j4 < 4; j4++)
                    #pragma unroll
                    for (int r = 0; r < 4; r++) o[j4][r] *= corr[r];
                pv(h);
            }
        }
    }

    float fin[4];
    #pragma unroll
    for (int r = 0; r < 4; r++) fin[r] = SCORE ? 1.f : (1.f / lr[r]);
    long obase = (((long)bh << 10) + rt * 64 + w * 16 + q * 4) * 64;
    #pragma unroll
    for (int j4 = 0; j4 < 4; j4++)
        #pragma unroll
        for (int r = 0; r < 4; r++)
            O[obase + (long)r * 64 + j4 * 16 + l15] = o[j4][r] * fin[r];
}

// topk with fused colsum-partial reduction (replaces score_reduce + old topk)
__global__ __launch_bounds__(256) void topk_kernel(const float* __restrict__ PSCW, int* __restrict__ topk) {
    __shared__ float s[1024];
    int z = blockIdx.x; int tid = threadIdx.x;
    for (int i = tid; i < 1024; i += 256) {
        float v = 0.f;
        for (int rw = 0; rw < 64; rw++) v += PSCW[(((long)z * 64 + rw) << 10) + i];
        s[i] = (v == v) ? v : -INFINITY;
    }
    __syncthreads();
    for (int i = tid; i < 1024; i += 256) {
        float si = s[i]; int r = 0;
        for (int j = 0; j < 1024; j++) {
            float sj = s[j];
            r += (sj > si) || (sj == si && j < i);
        }
        if (r < 256) topk[z * 256 + r] = i;
    }
}

__global__ __launch_bounds__(256) void gather_tokf_kernel(const float* __restrict__ coarse,
                                                          const int* __restrict__ topk,
                                                          float* __restrict__ tokf) {
    long idx = (long)blockIdx.x * 256 + threadIdx.x;
    int d = (int)(idx & 63); int t = (int)((idx >> 6) & 3);
    int j = (int)((idx >> 8) & 255); int bh = (int)(idx >> 16);
    int p = topk[bh * 256 + j] & 1023;
    int py = p >> 5, px = p & 31;
    int dy = t >> 1, dx = t & 1;
    int b = bh >> 2, h = bh & 3;
    tokf[idx] = coarse[(((long)b * 256 + h * 64 + d) * 64 + (2 * py + dy)) * 64 + (2 * px + dx)];
}

__global__ __launch_bounds__(256) void scatter_add_kernel(float* __restrict__ coarse,
                                                          const int* __restrict__ topk,
                                                          const float* __restrict__ outf) {
    long idx = (long)blockIdx.x * 256 + threadIdx.x;
    int d = (int)(idx & 63); int t = (int)((idx >> 6) & 3);
    int j = (int)((idx >> 8) & 255); int bh = (int)(idx >> 16);
    int p = topk[bh * 256 + j] & 1023;
    int py = p >> 5, px = p & 31;
    int dy = t >> 1, dx = t & 1;
    int b = bh >> 2, h = bh & 3;
    coarse[(((long)b * 256 + h * 64 + d) * 64 + (2 * py + dy)) * 64 + (2 * px + dx)] += outf[idx];
}

__global__ __launch_bounds__(64) void dw_bn_relu6_kernel(const float* __restrict__ y, const float* __restrict__ w9,
                                                         const float* __restrict__ s1, const float* __restrict__ t1,
                                                         float* __restrict__ out) {
    int gid = blockIdx.x;
    int row = gid & 63; int bc = gid >> 6; int c = bc & 255;
    int x = threadIdx.x;
    const float* base = y + (long)bc * 4096;
    float acc = 0.f;
    #pragma unroll
    for (int ky = 0; ky < 3; ky++) {
        int yy = row + ky - 1;
        if (yy < 0 || yy >= 64) continue;
        #pragma unroll
        for (int kx = 0; kx < 3; kx++) {
            int xx = x + kx - 1;
            if (xx < 0 || xx >= 64) continue;
            acc += base[yy * 64 + xx] * w9[c * 9 + ky * 3 + kx];
        }
    }
    out[(long)gid * 64 + x] = relu6(acc * s1[c] + t1[c]);
}

// ---------------- launch ----------------
extern "C" void kernel_launch(void* const* d_in, const int* in_sizes, int n_in,
                              void* d_out, int out_size, void* d_ws, size_t ws_size,
                              hipStream_t stream) {
    if (ws_size < (size_t)WS_FLOATS * 4) return;

    const void* x      = d_in[0];
    const void* down_w = d_in[1];
    const void* down_b = d_in[2];
    const void* up_w   = d_in[3];
    const void* up_b   = d_in[4];
    const void* wqkv_c = d_in[5];
    const void* bqkv_c = d_in[6];
    const void* wqkv_f = d_in[7];
    const void* bqkv_f = d_in[8];
    const void* dw_w   = d_in[9];
    const void* bn1_g  = d_in[10];
    const void* bn1_b  = d_in[11];
    const void* bn1_m  = d_in[12];
    const void* bn1_v  = d_in[13];
    const void* pw_w   = d_in[14];
    const void* bn2_g  = d_in[15];
    const void* bn2_b  = d_in[16];
    const void* bn2_m  = d_in[17];
    const void* bn2_v  = d_in[18];

    float* ws = (float*)d_ws;
    int* flagp = (int*)(ws + OFF_FLAG);
    dim3 blk(256);

    hipMemsetAsync(flagp, 0, sizeof(int), stream);
    detect_kernel<<<1, blk, 0, stream>>>(x, flagp);

    // split x and down_w into bf16 hi/lo
    split_pack_kernel<<<32768, blk, 0, stream>>>(x, (unsigned int*)(ws + OFF_XHL), 8388608, flagp);
    split_kernel<<<4096, blk, 0, stream>>>(down_w, (unsigned short*)(ws + OFF_DOWNW),
                                           (unsigned short*)(ws + OFF_DOWNWL), 1048576, flagp);
    prep_misc_kernel<<<367, blk, 0, stream>>>(down_b, up_b, bqkv_c, bqkv_f, dw_w, wqkv_c, wqkv_f, pw_w,
                                              bn1_g, bn1_b, bn1_m, bn1_v, bn2_g, bn2_b, bn2_m, bn2_v,
                                              ws, flagp);
    prep_up_kernel<<<4096, blk, 0, stream>>>(up_w, (unsigned short*)(ws + OFF_UPW4), flagp);

    // down conv (bf16x2 MFMA, topk-safe): M=8192, N=256, K=4096 -> xd NHWC
    gemm_mfma_x2<<<dim3(4, 128, 1), blk, 0, stream>>>((const unsigned int*)(ws + OFF_XHL),
        (const unsigned short*)(ws + OFF_DOWNW), (const unsigned short*)(ws + OFF_DOWNWL),
        ws + OFF_XDHWC, ws + OFF_DOWNB);

    // coarse qkv: M=32768, N=192, K=64 -> split bf16 planes (Q scaled)
    gemm_k<2><<<dim3(3, 512, 1), blk, 0, stream>>>(ws + OFF_XDHWC, ws + OFF_WQKVC,
        (unsigned short*)(ws + OFF_QH), 64, 64, 64, ws + OFF_BQKVC);

    // coarse MFMA attention (two-pass, + per-wave colsum partials) -> OUTC, PSCW
    attn_mfma<true><<<dim3(16, 32), blk, 0, stream>>>((const unsigned short*)(ws + OFF_QH),
        ws + OFF_OUTC, ws + OFF_PSCW);
    topk_kernel<<<32, blk, 0, stream>>>(ws + OFF_PSCW, (int*)(ws + OFF_TOPK));

    // up conv (bf16 MFMA, post-topk): M=8192, N=256, K=1024, z=cls -> coarse NCHW (overwrites XHL/PSCW)
    gemm_mfma<4, 2><<<dim3(4, 128, 4), blk, 0, stream>>>(ws + OFF_OUTC, (unsigned short*)(ws + OFF_UPW4),
        ws + OFF_COARSE, 1024, 0, 262144, 0, 1024, ws + OFF_UPB, nullptr, nullptr, flagp);

    // fine attention
    gather_tokf_kernel<<<8192, blk, 0, stream>>>(ws + OFF_COARSE, (const int*)(ws + OFF_TOPK), ws + OFF_XDHWC);
    gemm_k<3><<<dim3(3, 512, 1), blk, 0, stream>>>(ws + OFF_XDHWC, ws + OFF_WQKVF,
        (unsigned short*)(ws + OFF_QH), 64, 64, 64, ws + OFF_BQKVF);
    attn_mfma<false><<<dim3(16, 32), blk, 0, stream>>>((const unsigned short*)(ws + OFF_QH),
        ws + OFF_OUTC, nullptr);
    scatter_add_kernel<<<8192, blk, 0, stream>>>(ws + OFF_COARSE, (const int*)(ws + OFF_TOPK), ws + OFF_OUTC);

    // depthwise + bn1 + relu6 -> T1
    dw_bn_relu6_kernel<<<131072, dim3(64), 0, stream>>>(ws + OFF_COARSE, ws + OFF_DWW,
        ws + OFF_BN1S, ws + OFF_BN1T, ws + OFF_T1);

    // pointwise + bn2 + relu6 (bf16 MFMA) -> d_out: M=4096, N=256, K=256, z=batch
    gemm_mfma<5, 0><<<dim3(4, 64, 8), blk, 0, stream>>>(ws + OFF_T1, (unsigned short*)(ws + OFF_PWW),
        nullptr, 256, 1048576, 0, 4096, 256, ws + OFF_BN2S, ws + OFF_BN2T, d_out, flagp);
}

// Round 12
// 717.044 us; speedup vs baseline: 1.1802x; 1.0595x over previous
//
#include <hip/hip_runtime.h>
#include <hip/hip_bf16.h>

typedef __hip_bfloat16 bf16;
typedef __bf16 bf16x8 __attribute__((ext_vector_type(8)));
typedef float f32x4 __attribute__((ext_vector_type(4)));

// B=8, C=256, H=W=64, nh=4, HD=64, coarse tokens N=1024 (32x32), kf=256, fine tokens 1024.
// fp32 in/out (auto-detected). Top-k-critical paths (down-conv, attention QK^T) use bf16x2
// split-precision MFMA (error ~2^-17, fp32-class => tie-safe); PV + post-topk GEMMs plain bf16 MFMA.

// ---------------- workspace layout (float offsets) ----------------
#define OFF_XDHWC    0L
#define OFF_QH       2097152L     // 5 planes (ushort units vs this base):
                                  //   QH +0, QL +2097152, KH +4194304, KL +6291456, VT +8388608
#define OFF_T1       0L           // overlay on trunk
#define OFF_OUTC     8388608L
#define OFF_COARSE   10485760L    // XHL (packed hi|lo x) first, then PSCW, then coarse NCHW -> y
#define OFF_XHL      10485760L    // 8,388,608 uint (hi|lo packed bf16 of x, NCHW)
#define OFF_PSCW     10485760L    // 2M floats: per-(bh,rt,wave) colsum partials (XHL dead by then)
#define OFF_SCORE    19398656L
#define OFF_TOPK     19431424L
#define OFF_DOWNW    19439616L    // WH bf16 [co][k] (1M ushort); WL at +524288 floats
#define OFF_DOWNWL   19963904L
#define OFF_UPW4     20488192L    // bf16 (ushort) [cls][co][k]
#define OFF_WQKVC    21536768L
#define OFF_BQKVC    21549056L
#define OFF_WQKVF    21549248L
#define OFF_BQKVF    21561536L
#define OFF_PWW      21561728L    // bf16 (ushort) [co][ci]
#define OFF_DWW      21627264L
#define OFF_BN1S     21629568L
#define OFF_BN1T     21629824L
#define OFF_BN2S     21630080L
#define OFF_BN2T     21630336L
#define OFF_DOWNB    21630592L
#define OFF_UPB      21630848L
#define OFF_FLAG     21631104L    // 1 int: 1 = bf16 world, 0 = fp32 world (default via memset)
#define WS_FLOATS    21631360L

__device__ __forceinline__ float relu6(float v) { return v < 0.f ? 0.f : (v > 6.f ? 6.f : v); }

__device__ __forceinline__ float ldin(const void* p, long i, int flag) {
    return flag ? __bfloat162float(((const bf16*)p)[i]) : ((const float*)p)[i];
}

// fp32 -> bf16 bits, round-to-nearest-even
__device__ __forceinline__ unsigned short f2bf(float f) {
    unsigned int b = __float_as_uint(f);
    b += 0x7FFFu + ((b >> 16) & 1u);
    return (unsigned short)(b >> 16);
}

// ---------------- dtype detector ----------------
__global__ __launch_bounds__(256) void detect_kernel(const void* __restrict__ x, int* __restrict__ flag) {
    __shared__ int cnt[256];
    int tid = threadIdx.x;
    int c = 0;
    for (int i = tid; i < 4096; i += 256) {
        long idx = (long)i * 2047;
        float v = __bfloat162float(((const bf16*)x)[idx]);
        float a = fabsf(v);
        if (isfinite(v) && a > 1e-8f && a < 100.f) c++;
    }
    cnt[tid] = c; __syncthreads();
    for (int s = 128; s > 0; s >>= 1) { if (tid < s) cnt[tid] += cnt[tid + s]; __syncthreads(); }
    if (tid == 0 && cnt[0] >= 3686) *flag = 1;
}

// ---------------- prep kernels (dual-dtype) ----------------
// split to packed hi|lo uint (x): low16 = bf16(v), high16 = bf16(v - hi)
__global__ __launch_bounds__(256) void split_pack_kernel(const void* __restrict__ in, unsigned int* __restrict__ out,
                                                         int n, const int* __restrict__ flagp) {
    int flag = *flagp;
    int i = blockIdx.x * 256 + threadIdx.x;
    if (i < n) {
        float v = ldin(in, i, flag);
        unsigned short h = f2bf(v);
        float fh = __uint_as_float(((unsigned int)h) << 16);
        unsigned short l = f2bf(v - fh);
        out[i] = (unsigned int)h | ((unsigned int)l << 16);
    }
}

// split to separate hi/lo planes (down_w, layout [co][k] is identity with input flat layout)
__global__ __launch_bounds__(256) void split_kernel(const void* __restrict__ in,
                                                    unsigned short* __restrict__ hi, unsigned short* __restrict__ lo,
                                                    int n, const int* __restrict__ flagp) {
    int flag = *flagp;
    int i = blockIdx.x * 256 + threadIdx.x;
    if (i < n) {
        float v = ldin(in, i, flag);
        unsigned short h = f2bf(v);
        float fh = __uint_as_float(((unsigned int)h) << 16);
        hi[i] = h;
        lo[i] = f2bf(v - fh);
    }
}

// up_w [ci,co,4,4] -> W4 bf16 [cls][co][ci*4+j]
__global__ __launch_bounds__(256) void prep_up_kernel(const void* __restrict__ w, unsigned short* __restrict__ W4,
                                                      const int* __restrict__ flagp) {
    int flag = *flagp;
    int idx = blockIdx.x * 256 + threadIdx.x;
    int cls = idx >> 18; int rem = idx & 262143;
    int co = rem >> 10; int q = rem & 1023;
    int ci = q >> 2; int j = q & 3;
    int pa = cls >> 1, pb = cls & 1;
    int jy = j >> 1, jx = j & 1;
    int ky = (pa == 0) ? (jy ? 3 : 1) : (jy ? 0 : 2);
    int kx = (pb == 0) ? (jx ? 3 : 1) : (jx ? 0 : 2);
    W4[idx] = f2bf(ldin(w, (((long)ci * 256 + co) * 4 + ky) * 4 + kx, flag));
}

// fused small-tensor prep: tqkv_c, tqkv_f, dw_w, biases, bn1/bn2, pw_w (replaces 10 launches)
__global__ __launch_bounds__(256) void prep_misc_kernel(
    const void* __restrict__ down_b, const void* __restrict__ up_b,
    const void* __restrict__ bqkv_c, const void* __restrict__ bqkv_f,
    const void* __restrict__ dw_w, const void* __restrict__ wqkv_c,
    const void* __restrict__ wqkv_f, const void* __restrict__ pw_w,
    const void* __restrict__ bn1_g, const void* __restrict__ bn1_b,
    const void* __restrict__ bn1_m, const void* __restrict__ bn1_v,
    const void* __restrict__ bn2_g, const void* __restrict__ bn2_b,
    const void* __restrict__ bn2_m, const void* __restrict__ bn2_v,
    float* __restrict__ ws, const int* __restrict__ flagp)
{
    int flag = *flagp;
    int bid = blockIdx.x, tid = threadIdx.x;
    if (bid < 48) {                        // wqkv_c transpose -> [j][d]
        int idx = bid * 256 + tid;
        int j = idx >> 6, d = idx & 63;
        ws[OFF_WQKVC + idx] = ldin(wqkv_c, d * 192 + j, flag);
    } else if (bid < 96) {                 // wqkv_f transpose
        int idx = (bid - 48) * 256 + tid;
        int j = idx >> 6, d = idx & 63;
        ws[OFF_WQKVF + idx] = ldin(wqkv_f, d * 192 + j, flag);
    } else if (bid < 105) {                // dw_w cvt (2304)
        int i = (bid - 96) * 256 + tid;
        if (i < 2304) ws[OFF_DWW + i] = ldin(dw_w, i, flag);
    } else if (bid == 105) {
        ws[OFF_DOWNB + tid] = ldin(down_b, tid, flag);
    } else if (bid == 106) {
        ws[OFF_UPB + tid] = ldin(up_b, tid, flag);
    } else if (bid == 107) {
        if (tid < 192) ws[OFF_BQKVC + tid] = ldin(bqkv_c, tid, flag);
    } else if (bid == 108) {
        if (tid < 192) ws[OFF_BQKVF + tid] = ldin(bqkv_f, tid, flag);
    } else if (bid == 109) {               // bn1 prep
        float gv = ldin(bn1_g, tid, flag), bv = ldin(bn1_b, tid, flag);
        float mv = ldin(bn1_m, tid, flag), vv = ldin(bn1_v, tid, flag);
        float inv = gv / sqrtf(vv + 1e-5f);
        ws[OFF_BN1S + tid] = inv; ws[OFF_BN1T + tid] = bv - mv * inv;
    } else if (bid == 110) {               // bn2 prep
        float gv = ldin(bn2_g, tid, flag), bv = ldin(bn2_b, tid, flag);
        float mv = ldin(bn2_m, tid, flag), vv = ldin(bn2_v, tid, flag);
        float inv = gv / sqrtf(vv + 1e-5f);
        ws[OFF_BN2S + tid] = inv; ws[OFF_BN2T + tid] = bv - mv * inv;
    } else {                               // pw_w -> bf16 (65536), blocks 111..366
        int i = (bid - 111) * 256 + tid;
        ((unsigned short*)(ws + OFF_PWW))[i] = f2bf(ldin(pw_w, i, flag));
    }
}

// ---------------- bf16x2 split-precision MFMA down-conv (top-k-safe) ----------------
// R1-exact structure (best measured: 122.9us): 64x64 tile, BK=32, grid 4x128.
// C[m,n] = conv; m=(b,oy,ox) M=8192, n=co N=256, k=(ci,ky,kx) K=4096.
// A from XHL (packed hi|lo NCHW), B from WH/WL. 3-term MFMA: hihi + hilo + lohi.
__global__ __launch_bounds__(256) void gemm_mfma_x2(
    const unsigned int* __restrict__ XHL,
    const unsigned short* __restrict__ WH, const unsigned short* __restrict__ WL,
    float* __restrict__ C, const float* __restrict__ e0)
{
    __shared__ __align__(16) unsigned short Ah[64 * 40];
    __shared__ __align__(16) unsigned short Al[64 * 40];
    __shared__ __align__(16) unsigned short Bh[64 * 40];
    __shared__ __align__(16) unsigned short Bl[64 * 40];
    int m0 = blockIdx.y * 64, n0 = blockIdx.x * 64;
    int tid = threadIdx.x;
    int w = tid >> 6, l = tid & 63, l15 = l & 15, q = l >> 4;
    unsigned int aR[8];
    uint4 bhR, blR;
    int bn = tid >> 2, bk = (tid & 3) * 8;

    auto loadA = [&](int k0) {
        #pragma unroll
        for (int i = 0; i < 8; i++) {
            int idx = i * 256 + tid;
            int kl = idx & 31, ml = idx >> 5;
            int m = m0 + ml, k = k0 + kl;
            int b = m >> 10, oy = (m >> 5) & 31, ox = m & 31;
            int c = k >> 4, ky = (k >> 2) & 3, kx = k & 3;
            int iy = 2 * oy - 1 + ky, ix = 2 * ox - 1 + kx;
            unsigned int v = 0;
            if ((unsigned)iy < 64u && (unsigned)ix < 64u)
                v = XHL[(((long)b * 256 + c) * 64 + iy) * 64 + ix];
            aR[i] = v;
        }
    };
    auto storeA = [&]() {
        #pragma unroll
        for (int i = 0; i < 8; i++) {
            int idx = i * 256 + tid;
            int kl = idx & 31, ml = idx >> 5;
            Ah[ml * 40 + kl] = (unsigned short)(aR[i] & 0xffffu);
            Al[ml * 40 + kl] = (unsigned short)(aR[i] >> 16);
        }
    };
    auto loadB = [&](int k0) {
        bhR = *(const uint4*)(WH + (long)(n0 + bn) * 4096 + (k0 + bk));
        blR = *(const uint4*)(WL + (long)(n0 + bn) * 4096 + (k0 + bk));
    };

    f32x4 acc[4] = {};
    loadA(0); loadB(0);
    for (int k0 = 0; k0 < 4096; k0 += 32) {
        storeA();
        *(uint4*)(&Bh[bn * 40 + bk]) = bhR;
        *(uint4*)(&Bl[bn * 40 + bk]) = blR;
        __syncthreads();
        if (k0 + 32 < 4096) { loadA(k0 + 32); loadB(k0 + 32); }
        bf16x8 afh = *(const bf16x8*)(&Ah[(w * 16 + l15) * 40 + q * 8]);
        bf16x8 afl = *(const bf16x8*)(&Al[(w * 16 + l15) * 40 + q * 8]);
        #pragma unroll
        for (int j4 = 0; j4 < 4; j4++) {
            bf16x8 bfh = *(const bf16x8*)(&Bh[(j4 * 16 + l15) * 40 + q * 8]);
            bf16x8 bfl = *(const bf16x8*)(&Bl[(j4 * 16 + l15) * 40 + q * 8]);
            acc[j4] = __builtin_amdgcn_mfma_f32_16x16x32_bf16(afh, bfh, acc[j4], 0, 0, 0);
            acc[j4] = __builtin_amdgcn_mfma_f32_16x16x32_bf16(afh, bfl, acc[j4], 0, 0, 0);
            acc[j4] = __builtin_amdgcn_mfma_f32_16x16x32_bf16(afl, bfh, acc[j4], 0, 0, 0);
        }
        __syncthreads();
    }
    #pragma unroll
    for (int j4 = 0; j4 < 4; j4++) {
        int n = n0 + j4 * 16 + l15;
        #pragma unroll
        for (int r = 0; r < 4; r++) {
            int m = m0 + w * 16 + q * 4 + r;
            C[(long)m * 256 + n] = acc[j4][r] + e0[n];
        }
    }
}

// ---------------- fp32 GEMM (coarse/fine qkv) -> split bf16 planes for MFMA attention ----------
// C[m,n] = sum_k A[m,k]*B[n,k] + e0[n].  n<64 -> Q (x0.125, split hi/lo), n<128 -> K (split),
// else V -> transposed plain bf16 [bh][d][tok].
template<int EPI>
__global__ __launch_bounds__(256) void gemm_k(
    const float* __restrict__ A, const float* __restrict__ B,
    unsigned short* __restrict__ out, int K, int sAm, int sBn, const float* __restrict__ e0)
{
    __shared__ float As[16][68];
    __shared__ float Bs[16][68];
    int m0 = blockIdx.y * 64;
    int n0 = blockIdx.x * 64;
    int tid = threadIdx.x;
    int tx = tid & 15, ty = tid >> 4;
    int l4 = tid >> 2, kq = (tid & 3) * 4;
    float4 aR, bR;

    auto loadA = [&](int k0) { aR = *(const float4*)(A + (long)(m0 + l4) * sAm + (k0 + kq)); };
    auto loadB = [&](int k0) { bR = *(const float4*)(B + (long)(n0 + l4) * sBn + (k0 + kq)); };

    float acc[4][4] = {};
    loadA(0); loadB(0);
    for (int k0 = 0; k0 < K; k0 += 16) {
        As[kq + 0][l4] = aR.x; As[kq + 1][l4] = aR.y; As[kq + 2][l4] = aR.z; As[kq + 3][l4] = aR.w;
        Bs[kq + 0][l4] = bR.x; Bs[kq + 1][l4] = bR.y; Bs[kq + 2][l4] = bR.z; Bs[kq + 3][l4] = bR.w;
        __syncthreads();
        if (k0 + 16 < K) { loadA(k0 + 16); loadB(k0 + 16); }
        #pragma unroll
        for (int kk = 0; kk < 16; ++kk) {
            float4 av = *reinterpret_cast<const float4*>(&As[kk][ty * 4]);
            float4 bv = *reinterpret_cast<const float4*>(&Bs[kk][tx * 4]);
            float a[4] = {av.x, av.y, av.z, av.w};
            float b[4] = {bv.x, bv.y, bv.z, bv.w};
            #pragma unroll
            for (int i = 0; i < 4; i++)
                #pragma unroll
                for (int j = 0; j < 4; j++)
                    acc[i][j] += a[i] * b[j];
        }
        __syncthreads();
    }
    #pragma unroll
    for (int i = 0; i < 4; i++) {
        int m = m0 + ty * 4 + i;
        int bh, tok;
        if (EPI == 2) { int bi = m >> 12; int h = m & 3; tok = (m >> 2) & 1023; bh = bi * 4 + h; }
        else          { bh = m >> 10; tok = m & 1023; }
        #pragma unroll
        for (int j = 0; j < 4; j++) {
            int n = n0 + tx * 4 + j;
            float v = acc[i][j] + e0[n];
            if (n < 64) {
                v *= 0.125f;  // fold attention scale into Q
                unsigned short hb = f2bf(v);
                float fh = __uint_as_float(((unsigned int)hb) << 16);
                unsigned short lb = f2bf(v - fh);
                long p = (((long)bh << 10) + tok) * 64 + n;
                out[p] = hb; out[p + 2097152] = lb;
            } else if (n < 128) {
                unsigned short hb = f2bf(v);
                float fh = __uint_as_float(((unsigned int)hb) << 16);
                unsigned short lb = f2bf(v - fh);
                long p = (((long)bh << 10) + tok) * 64 + (n - 64);
                out[p + 4194304] = hb; out[p + 6291456] = lb;
            } else {
                out[8388608 + (((long)bh << 6) + (n - 128)) * 1024 + tok] = f2bf(v);
            }
        }
    }
}

// ---------------- bf16 MFMA GEMM (post-topk) ----------------
// AMODE==2 (up-conv): per-slot gather geometry is K-invariant -> hoist spatial base + validity;
// per-iter index math reduced to ci = ci0 + (k0>>2) and two shifts.
template<int EPI, int AMODE>
__global__ __launch_bounds__(256) void gemm_mfma(
    const float* __restrict__ A, const unsigned short* __restrict__ Bb, float* __restrict__ C,
    int K, long sAz, long sBz, int sAk, int sBn,
    const float* __restrict__ e0, const float* __restrict__ e1,
    void* __restrict__ ob, const int* __restrict__ flagp)
{
    __shared__ __align__(16) unsigned short Asb[64 * 40];
    __shared__ __align__(16) unsigned short Bsb[64 * 40];
    int z = blockIdx.z;
    if (AMODE == 0) A += (long)z * sAz;
    Bb += (long)z * sBz;
    int m0 = blockIdx.y * 64, n0 = blockIdx.x * 64;
    int tid = threadIdx.x;
    int w = tid >> 6, l = tid & 63;
    int l15 = l & 15, q = l >> 4;
    float aR[8];
    uint4 bR;

    int sbA[8], ci0A[8];
    if (AMODE != 0) {
        #pragma unroll
        for (int i = 0; i < 8; i++) {
            int idx = i * 256 + tid;
            int kl = idx & 31, ml = idx >> 5;
            int m = m0 + ml;
            int b = m >> 10, y = (m >> 5) & 31, x2 = m & 31;
            int j = kl & 3;
            int pa = z >> 1, pb = z & 1;
            int jy = j >> 1, jx = j & 1;
            int dy = (pa == 0) ? (jy ? -1 : 0) : (jy ? 1 : 0);
            int dx = (pb == 0) ? (jx ? -1 : 0) : (jx ? 1 : 0);
            int yy = y + dy, xx = x2 + dx;
            ci0A[i] = kl >> 2;
            sbA[i] = ((unsigned)yy < 32u && (unsigned)xx < 32u)
                     ? (b * 262144 + (yy * 32 + xx) * 64) : -1;
        }
    }

    auto loadA = [&](int k0) {
        if (AMODE == 0) {
            #pragma unroll
            for (int i = 0; i < 8; i++) {
                int idx = i * 256 + tid;
                int ml = idx & 63, kl = idx >> 6;
                aR[i] = A[(long)(k0 + kl) * sAk + (m0 + ml)];
            }
        } else {
            int cq = k0 >> 2;
            #pragma unroll
            for (int i = 0; i < 8; i++) {
                int ci = ci0A[i] + cq;
                aR[i] = (sbA[i] >= 0) ? A[sbA[i] + ((ci >> 6) << 16) + (ci & 63)] : 0.f;
            }
        }
    };
    auto storeA = [&]() {
        #pragma unroll
        for (int i = 0; i < 8; i++) {
            int idx = i * 256 + tid;
            int ml, kl;
            if (AMODE == 0) { ml = idx & 63; kl = idx >> 6; }
            else            { kl = idx & 31; ml = idx >> 5; }
            Asb[ml * 40 + kl] = f2bf(aR[i]);
        }
    };
    int bn = tid >> 2, bk = (tid & 3) * 8;
    auto loadB = [&](int k0) {
        bR = *(const uint4*)(Bb + (long)(n0 + bn) * sBn + (k0 + bk));
    };

    f32x4 acc[4] = {};
    loadA(0); loadB(0);
    for (int k0 = 0; k0 < K; k0 += 32) {
        storeA();
        *(uint4*)(&Bsb[bn * 40 + bk]) = bR;
        __syncthreads();
        if (k0 + 32 < K) { loadA(k0 + 32); loadB(k0 + 32); }
        bf16x8 af = *(const bf16x8*)(&Asb[(w * 16 + l15) * 40 + q * 8]);
        #pragma unroll
        for (int j4 = 0; j4 < 4; j4++) {
            bf16x8 bf = *(const bf16x8*)(&Bsb[(j4 * 16 + l15) * 40 + q * 8]);
            acc[j4] = __builtin_amdgcn_mfma_f32_16x16x32_bf16(af, bf, acc[j4], 0, 0, 0);
        }
        __syncthreads();
    }
    int oflag = (EPI == 5) ? *flagp : 0;
    #pragma unroll
    for (int j4 = 0; j4 < 4; j4++) {
        int n = n0 + j4 * 16 + l15;
        #pragma unroll
        for (int r = 0; r < 4; r++) {
            int m = m0 + w * 16 + q * 4 + r;
            float v = acc[j4][r];
            if (EPI == 4) {
                v += e0[n];
                int pa = z >> 1, pb = z & 1;
                int bi = m >> 10, y = (m >> 5) & 31, x2 = m & 31;
                C[(((long)bi * 256 + n) * 64 + (2 * y + pa)) * 64 + (2 * x2 + pb)] = v;
            } else {
                v = relu6(v * e0[n] + e1[n]);
                long oidx = (long)z * 1048576 + (long)n * 4096 + m;
                if (oflag) ((bf16*)ob)[oidx] = __float2bfloat16(v);
                else       ((float*)ob)[oidx] = v;
            }
        }
    }
}

// ---------------- MFMA attention: [bh=32][N=1024][D=64], scale folded into Q ----------------
// Planes (ushort offsets from P0): QH +0, QL +2097152, KH +4194304, KL +6291456, VT +8388608.
// QK^T: split-precision 3-term bf16x2 (fp32-class logits => topk-safe scores).
// PV:   plain bf16 (P normalized/bounded by 1; same error class as post-topk bf16 GEMMs).
// R11: stage 2 K-tiles (128 tokens) per barrier pair -> barriers 48->16 (SCORE) / 32->16
// (flash) per dispatch, load-latency exposures halved. Staging stays transient global->LDS
// (no persistent prefetch regs -- the R8/R9 spill lesson). LDS 63 KB, 2 blocks/CU unchanged.
template<bool SCORE>
__global__ __launch_bounds__(256) void attn_mfma(
    const unsigned short* __restrict__ P0,
    float* __restrict__ O, float* __restrict__ PSCW)
{
    const unsigned short* QH = P0;
    const unsigned short* QL = P0 + 2097152;
    const unsigned short* KH = P0 + 4194304;
    const unsigned short* KL = P0 + 6291456;
    const unsigned short* VT = P0 + 8388608;
    __shared__ __align__(16) unsigned short Khs[2][64 * 72];
    __shared__ __align__(16) unsigned short Kls[2][64 * 72];
    __shared__ __align__(16) unsigned short Vs[2][64 * 72];
    __shared__ __align__(16) unsigned short Ps[4][16 * 72];   // per-wave private P tile
    int bh = blockIdx.y, rt = blockIdx.x;
    int tid = threadIdx.x;
    int w = tid >> 6, l = tid & 63, l15 = l & 15, q = l >> 4;

    // Q fragments: rows rt*64 + w*16 + l15, dims kk*32 + q*8 (+0..7). Loaded once.
    long qoff = (((long)bh << 10) + rt * 64 + w * 16 + l15) * 64 + q * 8;
    bf16x8 afh[2], afl[2];
    afh[0] = *(const bf16x8*)(QH + qoff);
    afh[1] = *(const bf16x8*)(QH + qoff + 32);
    afl[0] = *(const bf16x8*)(QL + qoff);
    afl[1] = *(const bf16x8*)(QL + qoff + 32);

    float mr[4], lr[4];
    #pragma unroll
    for (int r = 0; r < 4; r++) { mr[r] = -1e30f; lr[r] = 0.f; }
    f32x4 o[4] = {};

    // stage 128 tokens (2 tiles) of K hi/lo
    auto stageK2 = [&](int tt) {
        #pragma unroll
        for (int i = 0; i < 4; i++) {
            int u = tid + i * 256;
            int tok = u >> 3, dp = (u & 7) * 8;   // tok 0..127
            int th = tok >> 6, tl = tok & 63;
            long g = (((long)bh << 10) + tt * 128 + tok) * 64 + dp;
            *(uint4*)(&Khs[th][tl * 72 + dp]) = *(const uint4*)(KH + g);
            *(uint4*)(&Kls[th][tl * 72 + dp]) = *(const uint4*)(KL + g);
        }
    };
    // stage 128 tokens (2 tiles) of V^T
    auto stageV2 = [&](int tt) {
        #pragma unroll
        for (int i = 0; i < 4; i++) {
            int u = tid + i * 256;
            int d = u >> 4, k0 = (u & 15) * 8;    // d 0..63, k0 0..120
            int th = k0 >> 6, kl = k0 & 63;
            long g = (((long)bh << 6) + d) * 1024 + tt * 128 + k0;
            *(uint4*)(&Vs[th][d * 72 + kl]) = *(const uint4*)(VT + g);
        }
    };
    auto computeS = [&](f32x4* s, int h) {
        #pragma unroll
        for (int kk = 0; kk < 2; kk++)
            #pragma unroll
            for (int j4 = 0; j4 < 4; j4++) {
                bf16x8 kh8 = *(const bf16x8*)(&Khs[h][(j4 * 16 + l15) * 72 + kk * 32 + q * 8]);
                bf16x8 kl8 = *(const bf16x8*)(&Kls[h][(j4 * 16 + l15) * 72 + kk * 32 + q * 8]);
                s[j4] = __builtin_amdgcn_mfma_f32_16x16x32_bf16(afh[kk], kh8, s[j4], 0, 0, 0);
                s[j4] = __builtin_amdgcn_mfma_f32_16x16x32_bf16(afh[kk], kl8, s[j4], 0, 0, 0);
                s[j4] = __builtin_amdgcn_mfma_f32_16x16x32_bf16(afl[kk], kh8, s[j4], 0, 0, 0);
            }
    };
    auto pv = [&](int h) {
        #pragma unroll
        for (int kk = 0; kk < 2; kk++) {
            bf16x8 ap = *(const bf16x8*)(&Ps[w][l15 * 72 + kk * 32 + q * 8]);
            #pragma unroll
            for (int j4 = 0; j4 < 4; j4++) {
                bf16x8 bv = *(const bf16x8*)(&Vs[h][(j4 * 16 + l15) * 72 + kk * 32 + q * 8]);
                o[j4] = __builtin_amdgcn_mfma_f32_16x16x32_bf16(ap, bv, o[j4], 0, 0, 0);
            }
        }
    };

    if (SCORE) {
        // ---- pass 1: row max + denom ----
        for (int tt = 0; tt < 8; ++tt) {
            __syncthreads();
            stageK2(tt);
            __syncthreads();
            #pragma unroll
            for (int h = 0; h < 2; ++h) {
                f32x4 s[4] = {};
                computeS(s, h);
                #pragma unroll
                for (int r = 0; r < 4; r++) {
                    float tm = fmaxf(fmaxf(s[0][r], s[1][r]), fmaxf(s[2][r], s[3][r]));
                    #pragma unroll
                    for (int off = 1; off < 16; off <<= 1) tm = fmaxf(tm, __shfl_xor(tm, off));
                    float mn = fmaxf(mr[r], tm);
                    float ss = __expf(s[0][r] - mn) + __expf(s[1][r] - mn)
                             + __expf(s[2][r] - mn) + __expf(s[3][r] - mn);
                    #pragma unroll
                    for (int off = 1; off < 16; off <<= 1) ss += __shfl_xor(ss, off);
                    lr[r] = lr[r] * __expf(mr[r] - mn) + ss;
                    mr[r] = mn;
                }
            }
        }
        float linv[4];
        #pragma unroll
        for (int r = 0; r < 4; r++) linv[r] = 1.f / lr[r];
        // ---- pass 2: normalized P, colsums, PV ----
        for (int tt = 0; tt < 8; ++tt) {
            __syncthreads();
            stageK2(tt); stageV2(tt);
            __syncthreads();
            #pragma unroll
            for (int h = 0; h < 2; ++h) {
                int t = tt * 2 + h;
                f32x4 s[4] = {};
                computeS(s, h);
                float cs[4] = {0.f, 0.f, 0.f, 0.f};
                #pragma unroll
                for (int j4 = 0; j4 < 4; j4++)
                    #pragma unroll
                    for (int r = 0; r < 4; r++) {
                        float p = __expf(s[j4][r] - mr[r]) * linv[r];
                        cs[j4] += p;
                        Ps[w][(q * 4 + r) * 72 + j4 * 16 + l15] = f2bf(p);
                    }
                #pragma unroll
                for (int j4 = 0; j4 < 4; j4++) {
                    cs[j4] += __shfl_xor(cs[j4], 16);
                    cs[j4] += __shfl_xor(cs[j4], 32);
                }
                if (q == 0) {
                    long pb = (((long)(bh * 16 + rt) * 4 + w) << 10) + t * 64;
                    #pragma unroll
                    for (int j4 = 0; j4 < 4; j4++) PSCW[pb + j4 * 16 + l15] = cs[j4];
                }
                pv(h);
            }
        }
    } else {
        // ---- single-pass online-softmax flash ----
        for (int tt = 0; tt < 8; ++tt) {
            __syncthreads();
            stageK2(tt); stageV2(tt);
            __syncthreads();
            #pragma unroll
            for (int h = 0; h < 2; ++h) {
                f32x4 s[4] = {};
                computeS(s, h);
                float corr[4];
                #pragma unroll
                for (int r = 0; r < 4; r++) {
                    float tm = fmaxf(fmaxf(s[0][r], s[1][r]), fmaxf(s[2][r], s[3][r]));
                    #pragma unroll
                    for (int off = 1; off < 16; off <<= 1) tm = fmaxf(tm, __shfl_xor(tm, off));
                    float mn = fmaxf(mr[r], tm);
                    corr[r] = __expf(mr[r] - mn);
                    mr[r] = mn;
                }
                float ssr[4] = {0.f, 0.f, 0.f, 0.f};
                #pragma unroll
                for (int j4 = 0; j4 < 4; j4++)
                    #pragma unroll
                    for (int r = 0; r < 4; r++) {
                        float p = __expf(s[j4][r] - mr[r]);
                        ssr[r] += p;
                        Ps[w][(q * 4 + r) * 72 + j4 * 16 + l15] = f2bf(p);
                    }
                #pragma unroll
                for (int r = 0; r < 4; r++) {
                    float ss = ssr[r];
                    #pragma unroll
                    for (int off = 1; off < 16; off <<= 1) ss += __shfl_xor(ss, off);
                    lr[r] = lr[r] * corr[r] + ss;
                }
                #pragma unroll
                for (int j4 = 0; j4 < 4; j4++)
                    #pragma unroll
                    for (int r = 0; r < 4; r++) o[j4][r] *= corr[r];
                pv(h);
            }
        }
    }

    float fin[4];
    #pragma unroll
    for (int r = 0; r < 4; r++) fin[r] = SCORE ? 1.f : (1.f / lr[r]);
    long obase = (((long)bh << 10) + rt * 64 + w * 16 + q * 4) * 64;
    #pragma unroll
    for (int j4 = 0; j4 < 4; j4++)
        #pragma unroll
        for (int r = 0; r < 4; r++)
            O[obase + (long)r * 64 + j4 * 16 + l15] = o[j4][r] * fin[r];
}

// topk with fused colsum-partial reduction (replaces score_reduce + old topk)
__global__ __launch_bounds__(256) void topk_kernel(const float* __restrict__ PSCW, int* __restrict__ topk) {
    __shared__ float s[1024];
    int z = blockIdx.x; int tid = threadIdx.x;
    for (int i = tid; i < 1024; i += 256) {
        float v = 0.f;
        for (int rw = 0; rw < 64; rw++) v += PSCW[(((long)z * 64 + rw) << 10) + i];
        s[i] = (v == v) ? v : -INFINITY;
    }
    __syncthreads();
    for (int i = tid; i < 1024; i += 256) {
        float si = s[i]; int r = 0;
        for (int j = 0; j < 1024; j++) {
            float sj = s[j];
            r += (sj > si) || (sj == si && j < i);
        }
        if (r < 256) topk[z * 256 + r] = i;
    }
}

__global__ __launch_bounds__(256) void gather_tokf_kernel(const float* __restrict__ coarse,
                                                          const int* __restrict__ topk,
                                                          float* __restrict__ tokf) {
    long idx = (long)blockIdx.x * 256 + threadIdx.x;
    int d = (int)(idx & 63); int t = (int)((idx >> 6) & 3);
    int j = (int)((idx >> 8) & 255); int bh = (int)(idx >> 16);
    int p = topk[bh * 256 + j] & 1023;
    int py = p >> 5, px = p & 31;
    int dy = t >> 1, dx = t & 1;
    int b = bh >> 2, h = bh & 3;
    tokf[idx] = coarse[(((long)b * 256 + h * 64 + d) * 64 + (2 * py + dy)) * 64 + (2 * px + dx)];
}

__global__ __launch_bounds__(256) void scatter_add_kernel(float* __restrict__ coarse,
                                                          const int* __restrict__ topk,
                                                          const float* __restrict__ outf) {
    long idx = (long)blockIdx.x * 256 + threadIdx.x;
    int d = (int)(idx & 63); int t = (int)((idx >> 6) & 3);
    int j = (int)((idx >> 8) & 255); int bh = (int)(idx >> 16);
    int p = topk[bh * 256 + j] & 1023;
    int py = p >> 5, px = p & 31;
    int dy = t >> 1, dx = t & 1;
    int b = bh >> 2, h = bh & 3;
    coarse[(((long)b * 256 + h * 64 + d) * 64 + (2 * py + dy)) * 64 + (2 * px + dx)] += outf[idx];
}

// R12: one block per (b,c) plane: stage 64x64 plane into zero-haloed 66x66 LDS tile,
// wave-uniform weights, each thread computes 16 outputs. Reads y exactly once
// (old version: 131072 one-wave blocks, ~3x read amplification, no reuse).
__global__ __launch_bounds__(256) void dw_bn_relu6_kernel(const float* __restrict__ y, const float* __restrict__ w9,
                                                          const float* __restrict__ s1, const float* __restrict__ t1,
                                                          float* __restrict__ out) {
    __shared__ float P[66 * 66];
    int bc = blockIdx.x;            // 2048 = b*256 + c
    int c = bc & 255;
    int tid = threadIdx.x;
    // zero halo (full clear, then interior fill)
    for (int i = tid; i < 66 * 66; i += 256) P[i] = 0.f;
    __syncthreads();
    const float* base = y + (long)bc * 4096;
    #pragma unroll
    for (int p = 0; p < 16; p++) {
        int i = p * 256 + tid;
        int r = i >> 6, cc = i & 63;
        P[(r + 1) * 66 + (cc + 1)] = base[i];
    }
    float w0 = w9[c * 9 + 0], w1 = w9[c * 9 + 1], w2 = w9[c * 9 + 2];
    float w3 = w9[c * 9 + 3], w4 = w9[c * 9 + 4], w5 = w9[c * 9 + 5];
    float w6 = w9[c * 9 + 6], w7 = w9[c * 9 + 7], w8 = w9[c * 9 + 8];
    float sc = s1[c], tc = t1[c];
    __syncthreads();
    float* ob = out + (long)bc * 4096;
    #pragma unroll
    for (int p = 0; p < 16; p++) {
        int i = p * 256 + tid;
        int r = i >> 6, cc = i & 63;
        const float* pr = &P[r * 66 + cc];      // top-left of 3x3 window (halo-shifted)
        float acc = pr[0] * w0 + pr[1] * w1 + pr[2] * w2
                  + pr[66] * w3 + pr[67] * w4 + pr[68] * w5
                  + pr[132] * w6 + pr[133] * w7 + pr[134] * w8;
        ob[i] = relu6(acc * sc + tc);
    }
}

// ---------------- launch ----------------
extern "C" void kernel_launch(void* const* d_in, const int* in_sizes, int n_in,
                              void* d_out, int out_size, void* d_ws, size_t ws_size,
                              hipStream_t stream) {
    if (ws_size < (size_t)WS_FLOATS * 4) return;

    const void* x      = d_in[0];
    const void* down_w = d_in[1];
    const void* down_b = d_in[2];
    const void* up_w   = d_in[3];
    const void* up_b   = d_in[4];
    const void* wqkv_c = d_in[5];
    const void* bqkv_c = d_in[6];
    const void* wqkv_f = d_in[7];
    const void* bqkv_f = d_in[8];
    const void* dw_w   = d_in[9];
    const void* bn1_g  = d_in[10];
    const void* bn1_b  = d_in[11];
    const void* bn1_m  = d_in[12];
    const void* bn1_v  = d_in[13];
    const void* pw_w   = d_in[14];
    const void* bn2_g  = d_in[15];
    const void* bn2_b  = d_in[16];
    const void* bn2_m  = d_in[17];
    const void* bn2_v  = d_in[18];

    float* ws = (float*)d_ws;
    int* flagp = (int*)(ws + OFF_FLAG);
    dim3 blk(256);

    hipMemsetAsync(flagp, 0, sizeof(int), stream);
    detect_kernel<<<1, blk, 0, stream>>>(x, flagp);

    // split x and down_w into bf16 hi/lo
    split_pack_kernel<<<32768, blk, 0, stream>>>(x, (unsigned int*)(ws + OFF_XHL), 8388608, flagp);
    split_kernel<<<4096, blk, 0, stream>>>(down_w, (unsigned short*)(ws + OFF_DOWNW),
                                           (unsigned short*)(ws + OFF_DOWNWL), 1048576, flagp);
    prep_misc_kernel<<<367, blk, 0, stream>>>(down_b, up_b, bqkv_c, bqkv_f, dw_w, wqkv_c, wqkv_f, pw_w,
                                              bn1_g, bn1_b, bn1_m, bn1_v, bn2_g, bn2_b, bn2_m, bn2_v,
                                              ws, flagp);
    prep_up_kernel<<<4096, blk, 0, stream>>>(up_w, (unsigned short*)(ws + OFF_UPW4), flagp);

    // down conv (bf16x2 MFMA, topk-safe): M=8192, N=256, K=4096 -> xd NHWC
    gemm_mfma_x2<<<dim3(4, 128, 1), blk, 0, stream>>>((const unsigned int*)(ws + OFF_XHL),
        (const unsigned short*)(ws + OFF_DOWNW), (const unsigned short*)(ws + OFF_DOWNWL),
        ws + OFF_XDHWC, ws + OFF_DOWNB);

    // coarse qkv: M=32768, N=192, K=64 -> split bf16 planes (Q scaled)
    gemm_k<2><<<dim3(3, 512, 1), blk, 0, stream>>>(ws + OFF_XDHWC, ws + OFF_WQKVC,
        (unsigned short*)(ws + OFF_QH), 64, 64, 64, ws + OFF_BQKVC);

    // coarse MFMA attention (two-pass, + per-wave colsum partials) -> OUTC, PSCW
    attn_mfma<true><<<dim3(16, 32), blk, 0, stream>>>((const unsigned short*)(ws + OFF_QH),
        ws + OFF_OUTC, ws + OFF_PSCW);
    topk_kernel<<<32, blk, 0, stream>>>(ws + OFF_PSCW, (int*)(ws + OFF_TOPK));

    // up conv (bf16 MFMA, post-topk): M=8192, N=256, K=1024, z=cls -> coarse NCHW (overwrites XHL/PSCW)
    gemm_mfma<4, 2><<<dim3(4, 128, 4), blk, 0, stream>>>(ws + OFF_OUTC, (unsigned short*)(ws + OFF_UPW4),
        ws + OFF_COARSE, 1024, 0, 262144, 0, 1024, ws + OFF_UPB, nullptr, nullptr, flagp);

    // fine attention
    gather_tokf_kernel<<<8192, blk, 0, stream>>>(ws + OFF_COARSE, (const int*)(ws + OFF_TOPK), ws + OFF_XDHWC);
    gemm_k<3><<<dim3(3, 512, 1), blk, 0, stream>>>(ws + OFF_XDHWC, ws + OFF_WQKVF,
        (unsigned short*)(ws + OFF_QH), 64, 64, 64, ws + OFF_BQKVF);
    attn_mfma<false><<<dim3(16, 32), blk, 0, stream>>>((const unsigned short*)(ws + OFF_QH),
        ws + OFF_OUTC, nullptr);
    scatter_add_kernel<<<8192, blk, 0, stream>>>(ws + OFF_COARSE, (const int*)(ws + OFF_TOPK), ws + OFF_OUTC);

    // depthwise + bn1 + relu6 -> T1 (plane-per-block, LDS-staged)
    dw_bn_relu6_kernel<<<2048, blk, 0, stream>>>(ws + OFF_COARSE, ws + OFF_DWW,
        ws + OFF_BN1S, ws + OFF_BN1T, ws + OFF_T1);

    // pointwise + bn2 + relu6 (bf16 MFMA) -> d_out: M=4096, N=256, K=256, z=batch
    gemm_mfma<5, 0><<<dim3(4, 64, 8), blk, 0, stream>>>(ws + OFF_T1, (unsigned short*)(ws + OFF_PWW),
        nullptr, 256, 1048576, 0, 4096, 256, ws + OFF_BN2S, ws + OFF_BN2T, d_out, flagp);
}